// Round 7
// baseline (419.035 us; speedup 1.0000x reference)
//
#include <hip/hip_runtime.h>
#include <math.h>

typedef unsigned short u16;
typedef unsigned int u32;
typedef short bf16x8 __attribute__((ext_vector_type(8)));
typedef float f32x4 __attribute__((ext_vector_type(4)));

#define MFMA(a, b, c) __builtin_amdgcn_mfma_f32_16x16x32_bf16((a), (b), (c), 0, 0, 0)

// async global->LDS, 16B per lane; LDS dest = wave-uniform base + lane*16
#define GLOAD_LDS16(g, l)                                                              \
    __builtin_amdgcn_global_load_lds((const __attribute__((address_space(1))) void*)(g), \
                                     (__attribute__((address_space(3))) void*)(l), 16, 0, 0)

__device__ __forceinline__ u16 f2bf(float f) {
    u32 u = __float_as_uint(f);
    u32 r = (u + 0x7fffu + ((u >> 16) & 1u)) >> 16;
    return (u16)r;
}

__device__ __forceinline__ u16 f2bf_trunc(float f) {  // truncating bf16 (1 VALU op)
    return (u16)(__float_as_uint(f) >> 16);
}

// tanh-form GELU via native exp/rcp
__device__ __forceinline__ float fast_gelu(float z) {
    float u = fminf(1.5957691216f * z * (1.0f + 0.044715f * z * z), 80.0f);
    float e = __expf(u);
    float r = __builtin_amdgcn_rcpf(e + 1.0f);
    return z * e * r;
}

// ================= fused prep: x cast + all weight transposes, one dispatch =================
__device__ void dev_xcast(const float* __restrict__ in, u16* __restrict__ out, int blk) {
    size_t i = ((size_t)blk * 256 + threadIdx.x) * 8;
    const float4* p = reinterpret_cast<const float4*>(in + i);
    float4 a = p[0], b = p[1];
    union { u16 u[8]; uint4 v; } o;
    o.u[0] = f2bf(a.x); o.u[1] = f2bf(a.y); o.u[2] = f2bf(a.z); o.u[3] = f2bf(a.w);
    o.u[4] = f2bf(b.x); o.u[5] = f2bf(b.y); o.u[6] = f2bf(b.z); o.u[7] = f2bf(b.w);
    *reinterpret_cast<uint4*>(out + i) = o.v;
}

__device__ void dev_transpose(const float* __restrict__ in, u16* __restrict__ out,
                              int K, int N, int bx, int by, float* tile /* [64][65] */) {
    int k0 = by * 64, n0 = bx * 64;
    int t = threadIdx.x;
    for (int p = 0; p < 16; p++) {
        int idx = t + p * 256;
        int r = idx >> 6, c = idx & 63;
        tile[r * 65 + c] = in[(size_t)(k0 + r) * N + n0 + c];
    }
    __syncthreads();
    for (int p = 0; p < 16; p++) {
        int idx = t + p * 256;
        int nr = idx >> 6, nc = idx & 63;
        out[(size_t)(n0 + nr) * K + k0 + nc] = f2bf(tile[nc * 65 + nr]);
    }
}

// Wo transpose with k-permute: out[col][n*64+d] = Wo[d*12+n][col]
__device__ void dev_wo(const float* __restrict__ in, u16* __restrict__ out,
                       int bx, int by, float* tile /* [96][65] */) {
    int k0 = by * 96, n0 = bx * 64;
    int t = threadIdx.x;
    for (int p = 0; p < 24; p++) {
        int idx = t + p * 256;
        int r = idx >> 6, c = idx & 63;
        tile[r * 65 + c] = in[(size_t)(k0 + r) * 768 + n0 + c];
    }
    __syncthreads();
    for (int p = 0; p < 3; p++) {
        int idx = t + p * 256;  // (col c)*12 + n
        int c = idx / 12, n = idx % 12;
        union { u16 u[8]; uint4 v; } o;
        for (int j = 0; j < 8; j++) o.u[j] = f2bf(tile[(j * 12 + n) * 65 + c]);
        *reinterpret_cast<uint4*>(&out[(size_t)(n0 + c) * 768 + n * 64 + by * 8]) = o.v;
    }
}

__global__ __launch_bounds__(256) void prep_k(const float* __restrict__ x,
                                              const float* __restrict__ Wq,
                                              const float* __restrict__ Wk,
                                              const float* __restrict__ Wo,
                                              const float* __restrict__ W1,
                                              const float* __restrict__ W2,
                                              u16* __restrict__ XB,
                                              u16* __restrict__ WQKT,
                                              u16* __restrict__ WOT,
                                              u16* __restrict__ W1T,
                                              u16* __restrict__ W2T) {
    __shared__ float tile[96 * 65];
    int bid = blockIdx.x;
    if (bid < 3072) {
        dev_xcast(x, XB, bid);
    } else if (bid < 3216) {
        int b = bid - 3072; dev_transpose(Wq, WQKT, 768, 768, b % 12, b / 12, tile);
    } else if (bid < 3360) {
        int b = bid - 3216; dev_transpose(Wk, WQKT + (size_t)768 * 768, 768, 768, b % 12, b / 12, tile);
    } else if (bid < 3456) {
        int b = bid - 3360; dev_wo(Wo, WOT, b % 12, b / 12, tile);
    } else if (bid < 4032) {
        int b = bid - 3456; dev_transpose(W1, W1T, 768, 3072, b % 48, b / 48, tile);
    } else {
        int b = bid - 4032; dev_transpose(W2, W2T, 3072, 768, b % 12, b / 12, tile);
    }
}

// ---------------- head pack: in (S x ld, col base pre-offset) -> KH (96 x 1024 x 64) ----------------
// Also emits KHT (96 x 64 x 1024): KHT[head][d][m] = K[b][m][d*12+n], so the attention
// kernel can stage its transposed K tile with vector loads instead of 16 scalar LDS writes.
__global__ __launch_bounds__(256) void head_pack_k(const u16* __restrict__ in, int ld,
                                                   u16* __restrict__ out,
                                                   u16* __restrict__ outT) {
    __shared__ u16 tile[16 * 768];
    int b = blockIdx.y;
    int l0 = blockIdx.x * 16;
    int t = threadIdx.x;
    for (int p = 0; p < 6; p++) {
        int c = t + p * 256;
        int li = c / 96, dc = c % 96;
        *reinterpret_cast<uint4*>(&tile[li * 768 + dc * 8]) =
            *reinterpret_cast<const uint4*>(&in[(size_t)(b * 1024 + l0 + li) * ld + dc * 8]);
    }
    __syncthreads();
    for (int p = 0; p < 6; p++) {
        int c = t + p * 256;
        int n = c >> 7, rem = c & 127, li = rem >> 3, k8 = rem & 7;
        union { u16 u[8]; uint4 v; } o;
        for (int j = 0; j < 8; j++) o.u[j] = tile[li * 768 + (k8 * 8 + j) * 12 + n];
        *reinterpret_cast<uint4*>(&out[(size_t)((b * 12 + n) * 1024 + l0 + li) * 64 + k8 * 8]) = o.v;
    }
    // transposed copy: 6 passes x 256 threads cover 12 heads x 64 d x 2 halves (8 m each)
    for (int p = 0; p < 6; p++) {
        int c = t + p * 256;                 // 0..1535
        int n = c >> 7;                      // head 0..11
        int rem = c & 127;
        int d = rem >> 1;                    // 0..63
        int half = rem & 1;                  // m-offset 0 or 8
        union { u16 u[8]; uint4 v; } o;
        for (int j = 0; j < 8; j++) o.u[j] = tile[(half * 8 + j) * 768 + d * 12 + n];
        *reinterpret_cast<uint4*>(
            &outT[((size_t)(b * 12 + n) * 64 + d) * 1024 + l0 + half * 8]) = o.v;
    }
}

// ---------------- GEMM: C(MxN) = A(MxK bf16) @ BT(NxK bf16)^T ----------------
// TM x 128 tile, NS-stage pipeline, ONE raw s_barrier per K-step, counted vmcnt (never 0
// except NS=2). K-loop unrolled in groups of NS (compile-time stage indices).
// XCD swizzle: column-blocks sharing an A-stripe -> same XCD.
// AH: A is CTXH [b*12+n][l][64], logical k = n*64+d (TM=64; BT rows permuted).
// KSPLIT: grid doubled; second half computes K-range [K/2,K) into outF2 (=outB as float*),
//         first half does the full epilogue on K-range [0,K/2). Reduction fused into next LN.
// EPI 1: outF = resid + acc;  2: outB = bf16(gelu(acc + bias[col]));
// EPI 3: outF = resid + acc + bias[col];
// EPI 4: outB = bf16(acc * (col<768 ? 0.125*log2e : 1))  [QK proj; Q in log2-domain]
template <int EPI, int TM, bool AH = false, int NSO = 0, bool KSPLIT = false>
__global__ __launch_bounds__(256) void gemm_bt_k(const u16* __restrict__ A,
                                                 const u16* __restrict__ BT,
                                                 int M, int N, int K, int NBX,
                                                 float* __restrict__ outF,
                                                 u16* __restrict__ outB,
                                                 const float* __restrict__ resid,
                                                 const float* __restrict__ bias) {
    constexpr int MI = TM / 32;
    constexpr int NS = NSO ? NSO : ((TM == 64) ? 4 : 3);
    constexpr int LPS = (TM == 128) ? 4 : 3;   // loads per K-step per thread
    constexpr int VC = LPS * (NS - 2);         // counted vmcnt at the wait point
    __shared__ __align__(16) u16 As[NS][TM * 32];
    __shared__ __align__(16) u16 Bs[NS][128 * 32];

    int L = blockIdx.x;
    int kp = 0;
    if constexpr (KSPLIT) {
        int half = gridDim.x >> 1;
        if (L >= half) { kp = 1; L -= half; }
    }
    int bx = (L >> 3) % NBX;
    int by = (L / (8 * NBX)) * 8 + (L & 7);
    int m0 = by * TM, n0 = bx * 128;

    int t = threadIdx.x;
    int wave = t >> 6, lane = t & 63;
    int wr = (wave >> 1) * (TM / 2), wc = (wave & 1) * 64;
    int ln = lane & 15, quad = lane >> 4;
    int sw = quad ^ ((ln >> 1) & 3);

    int e0 = t, e1 = t + 256;
    int r0 = e0 >> 2, c0 = (e0 & 3) ^ ((r0 >> 1) & 3);
    int r1 = e1 >> 2, c1 = (e1 & 3) ^ ((r1 >> 1) & 3);
    int kofs = 0;
    if constexpr (KSPLIT) kofs = kp * (K >> 1);
    int ahk = 0;  // AH: col8 offset for the K-split upper half (K/16 col8 groups)
    if constexpr (KSPLIT && AH) ahk = kp * (K >> 4);
    const u16* A0 = A + (size_t)(m0 + r0) * K + kofs + c0 * 8;
    const u16* A1 = A + (size_t)(m0 + r1) * K + kofs + c1 * 8;  // TM==128 only
    const u16* B0 = BT + (size_t)(n0 + r0) * K + kofs + c0 * 8;
    const u16* B1 = BT + (size_t)(n0 + r1) * K + kofs + c1 * 8;
    const u16* Abase = nullptr;
    if constexpr (AH) {
        int m = m0 + r0;
        Abase = A + ((size_t)(m >> 10) * 12288 + (m & 1023)) * 64;
    }

    int nk = K >> 5;  // multiple of NS for all shapes here
    if constexpr (KSPLIT) nk >>= 1;

    f32x4 acc[MI][4];
    for (int i = 0; i < MI; i++)
        for (int j = 0; j < 4; j++)
            for (int r = 0; r < 4; r++) acc[i][j][r] = 0.0f;

    for (int s = 0; s < NS - 1; s++) {
        if constexpr (AH) {
            int col8 = ahk + s * 4 + c0;
            GLOAD_LDS16(Abase + (col8 >> 3) * 65536 + (col8 & 7) * 8, &As[s][e0 * 8]);
        } else {
            GLOAD_LDS16(A0 + s * 32, &As[s][e0 * 8]);
            if constexpr (TM == 128) GLOAD_LDS16(A1 + s * 32, &As[s][e1 * 8]);
        }
        GLOAD_LDS16(B0 + s * 32, &Bs[s][e0 * 8]);
        GLOAD_LDS16(B1 + s * 32, &Bs[s][e1 * 8]);
    }

    for (int kb = 0; kb < nk; kb += NS) {
#pragma unroll
        for (int s = 0; s < NS; s++) {
            int k = kb + s;
            if constexpr (VC == 6)      asm volatile("s_waitcnt vmcnt(6)" ::: "memory");
            else if constexpr (VC == 4) asm volatile("s_waitcnt vmcnt(4)" ::: "memory");
            else if constexpr (VC == 3) asm volatile("s_waitcnt vmcnt(3)" ::: "memory");
            else                        asm volatile("s_waitcnt vmcnt(0)" ::: "memory");
            asm volatile("s_barrier" ::: "memory");
            {
                int ks = k + NS - 1 < nk ? k + NS - 1 : nk - 1;  // clamped: uniform in-flight count
                int stage = (s + NS - 1) % NS;  // s constant under unroll -> folds
                if constexpr (AH) {
                    int col8 = ahk + ks * 4 + c0;
                    GLOAD_LDS16(Abase + (col8 >> 3) * 65536 + (col8 & 7) * 8, &As[stage][e0 * 8]);
                } else {
                    GLOAD_LDS16(A0 + ks * 32, &As[stage][e0 * 8]);
                    if constexpr (TM == 128) GLOAD_LDS16(A1 + ks * 32, &As[stage][e1 * 8]);
                }
                GLOAD_LDS16(B0 + ks * 32, &Bs[stage][e0 * 8]);
                GLOAD_LDS16(B1 + ks * 32, &Bs[stage][e1 * 8]);
            }
            const u16* as = As[s];
            const u16* bs = Bs[s];
            bf16x8 afr[MI], bfr[4];
            for (int i = 0; i < MI; i++)
                afr[i] = *reinterpret_cast<const bf16x8*>(&as[(wr + i * 16 + ln) * 32 + sw * 8]);
            for (int j = 0; j < 4; j++)
                bfr[j] = *reinterpret_cast<const bf16x8*>(&bs[(wc + j * 16 + ln) * 32 + sw * 8]);
            for (int i = 0; i < MI; i++)
                for (int j = 0; j < 4; j++)
                    acc[i][j] = MFMA(afr[i], bfr[j], acc[i][j]);
        }
    }

    for (int i = 0; i < MI; i++) {
        for (int j = 0; j < 4; j++) {
            int col = n0 + wc + j * 16 + ln;
            for (int r = 0; r < 4; r++) {
                int row = m0 + wr + i * 16 + quad * 4 + r;
                size_t idx = (size_t)row * N + col;
                float v = acc[i][j][r];
                if constexpr (EPI == 1) {
                    if constexpr (KSPLIT) {
                        if (kp == 0) outF[idx] = resid[idx] + v;
                        else reinterpret_cast<float*>(outB)[idx] = v;
                    } else {
                        outF[idx] = resid[idx] + v;
                    }
                } else if constexpr (EPI == 2) {
                    outB[idx] = f2bf(fast_gelu(v + bias[col]));
                } else if constexpr (EPI == 3) {
                    if constexpr (KSPLIT) {
                        if (kp == 0) outF[idx] = resid[idx] + v + bias[col];
                        else reinterpret_cast<float*>(outB)[idx] = v;
                    } else {
                        outF[idx] = resid[idx] + v + bias[col];
                    }
                } else {
                    // 0.125 * log2(e): Q scores land in log2 domain for exp2 softmax
                    outB[idx] = f2bf(col < 768 ? v * 0.18033688011112042f : v);
                }
            }
        }
    }
}

// ---------------- flash-style attention (ctx = softmax @ K), Q prescaled to log2 domain ----------------
// QB row-major (ldq), KH head-major, KHT head-major-transposed [head][d][m].
// p = exp2(st) (no max, no clamp: st ~ N(0,1.44)).
// P-tile: plain stride 72 (r5-measured fewer conflicts than XOR-64). P stored truncated.
// KsT staged with 2 vector loads + 2 ds_write_b128 (was: 16 scalar ds_write_b16).
__global__ __launch_bounds__(256) void attention_k(const u16* __restrict__ QB, int ldq,
                                                   const u16* __restrict__ KH,
                                                   const u16* __restrict__ KHT,
                                                   u16* __restrict__ CTXH) {
    __shared__ __align__(16) u16 Ks[64 * 72];   // [m'][d]
    __shared__ __align__(16) u16 KsT[64 * 72];  // [d][m']
    __shared__ __align__(16) u16 Pl[4][16 * 72];
    int bh = blockIdx.y;
    int b = bh / 12, n = bh % 12;
    int l0 = blockIdx.x * 64;
    int t = threadIdx.x, wave = t >> 6, lane = t & 63;
    int ln = lane & 15, quad = lane >> 4;
    int lw = l0 + wave * 16;

    // Q A-fragments (strided gather, once per block); Q already scaled by 0.125*log2e
    bf16x8 a0, a1;
    {
        union { u16 u[8]; bf16x8 v; } q0, q1;
        const u16* qrow = QB + (size_t)(b * 1024 + lw + ln) * ldq + n;
        for (int j = 0; j < 8; j++) {
            q0.u[j] = qrow[(quad * 8 + j) * 12];
            q1.u[j] = qrow[(32 + quad * 8 + j) * 12];
        }
        a0 = q0.v; a1 = q1.v;
    }

    f32x4 o[4];
    for (int dt = 0; dt < 4; dt++)
        for (int r = 0; r < 4; r++) o[dt][r] = 0.0f;
    float lst[4];
    for (int r = 0; r < 4; r++) lst[r] = 0.0f;

    const u16* Kbase  = KH  + (size_t)bh * 65536;
    const u16* KTbase = KHT + (size_t)bh * 65536;  // [d][m], 64 rows x 1024
    int mi = t & 63, ds = (t >> 6) * 16;

    uint4 kva = *reinterpret_cast<const uint4*>(&Kbase[(size_t)mi * 64 + ds]);
    uint4 kvb = *reinterpret_cast<const uint4*>(&Kbase[(size_t)mi * 64 + ds + 8]);
    uint4 kta = *reinterpret_cast<const uint4*>(&KTbase[(size_t)mi * 1024 + ds]);
    uint4 ktb = *reinterpret_cast<const uint4*>(&KTbase[(size_t)mi * 1024 + ds + 8]);

    for (int mb = 0; mb < 16; mb++) {
        __syncthreads();
        *reinterpret_cast<uint4*>(&Ks[mi * 72 + ds]) = kva;
        *reinterpret_cast<uint4*>(&Ks[mi * 72 + ds + 8]) = kvb;
        *reinterpret_cast<uint4*>(&KsT[mi * 72 + ds]) = kta;
        *reinterpret_cast<uint4*>(&KsT[mi * 72 + ds + 8]) = ktb;
        __syncthreads();

        {
            int mnext = (mb + 1 < 16 ? mb + 1 : 15) * 64;
            kva = *reinterpret_cast<const uint4*>(&Kbase[(size_t)(mnext + mi) * 64 + ds]);
            kvb = *reinterpret_cast<const uint4*>(&Kbase[(size_t)(mnext + mi) * 64 + ds + 8]);
            kta = *reinterpret_cast<const uint4*>(&KTbase[(size_t)mi * 1024 + mnext + ds]);
            ktb = *reinterpret_cast<const uint4*>(&KTbase[(size_t)mi * 1024 + mnext + ds + 8]);
        }

        f32x4 st[4];
        for (int nt = 0; nt < 4; nt++) {
            bf16x8 bk0 = *reinterpret_cast<bf16x8*>(&Ks[(nt * 16 + ln) * 72 + quad * 8]);
            bf16x8 bk1 = *reinterpret_cast<bf16x8*>(&Ks[(nt * 16 + ln) * 72 + 32 + quad * 8]);
            f32x4 z;
            for (int r = 0; r < 4; r++) z[r] = 0.0f;
            z = MFMA(a0, bk0, z);
            st[nt] = MFMA(a1, bk1, z);
        }

        // softmax numerator: p = exp2(st) (st already includes 1/8 * log2e); no max, no clamp
        for (int r = 0; r < 4; r++) {
            int row = quad * 4 + r;
            float psum = 0.0f;
            for (int nt = 0; nt < 4; nt++) {
                float p = exp2f(st[nt][r]);
                psum += p;
                Pl[wave][row * 72 + nt * 16 + ln] = f2bf_trunc(p);
            }
            lst[r] += psum;
        }

        // PV: O += P(16x64) @ K(64x64)   (Pl wave-private: no barrier)
        bf16x8 pf0 = *reinterpret_cast<bf16x8*>(&Pl[wave][ln * 72 + quad * 8]);
        bf16x8 pf1 = *reinterpret_cast<bf16x8*>(&Pl[wave][ln * 72 + 32 + quad * 8]);
        for (int dt = 0; dt < 4; dt++) {
            bf16x8 bk0 = *reinterpret_cast<bf16x8*>(&KsT[(dt * 16 + ln) * 72 + quad * 8]);
            bf16x8 bk1 = *reinterpret_cast<bf16x8*>(&KsT[(dt * 16 + ln) * 72 + 32 + quad * 8]);
            o[dt] = MFMA(pf0, bk0, o[dt]);
            o[dt] = MFMA(pf1, bk1, o[dt]);
        }
    }

    for (int r = 0; r < 4; r++)
        for (int off = 1; off < 16; off <<= 1) lst[r] += __shfl_xor(lst[r], off, 64);

    u16* out = CTXH + (size_t)bh * 65536;
    for (int r = 0; r < 4; r++) {
        float inv = 1.0f / lst[r];
        int row = lw + quad * 4 + r;
        for (int dt = 0; dt < 4; dt++)
            out[(size_t)row * 64 + dt * 16 + ln] = f2bf(o[dt][r] * inv);
    }
}

// ---------------- layernorm over 768, one block per row; optional second input (K-split reduce) ----------------
__global__ __launch_bounds__(256) void layernorm_k(const float* __restrict__ in,
                                                   float* __restrict__ outF,
                                                   u16* __restrict__ outB,
                                                   const float* __restrict__ g,
                                                   const float* __restrict__ be,
                                                   const float* __restrict__ in2) {
    __shared__ float red[8];
    int row = blockIdx.x;
    int t = threadIdx.x;
    const float* p = in + (size_t)row * 768;
    float v0 = p[t], v1 = p[t + 256], v2 = p[t + 512];
    if (in2) {
        const float* p2 = in2 + (size_t)row * 768;
        v0 += p2[t]; v1 += p2[t + 256]; v2 += p2[t + 512];
    }
    float s = v0 + v1 + v2;
    float ss = v0 * v0 + v1 * v1 + v2 * v2;
    for (int off = 32; off >= 1; off >>= 1) {
        s += __shfl_xor(s, off, 64);
        ss += __shfl_xor(ss, off, 64);
    }
    int wave = t >> 6, lane = t & 63;
    if (lane == 0) { red[wave] = s; red[4 + wave] = ss; }
    __syncthreads();
    float S = red[0] + red[1] + red[2] + red[3];
    float SS = red[4] + red[5] + red[6] + red[7];
    float mean = S * (1.0f / 768.0f);
    float var = SS * (1.0f / 768.0f) - mean * mean;
    float rstd = rsqrtf(var + 1e-5f);
    float o0 = (v0 - mean) * rstd * g[t] + be[t];
    float o1 = (v1 - mean) * rstd * g[t + 256] + be[t + 256];
    float o2 = (v2 - mean) * rstd * g[t + 512] + be[t + 512];
    float* q = outF + (size_t)row * 768;
    q[t] = o0; q[t + 256] = o1; q[t + 512] = o2;
    if (outB) {
        u16* qb = outB + (size_t)row * 768;
        qb[t] = f2bf(o0); qb[t + 256] = f2bf(o1); qb[t + 512] = f2bf(o2);
    }
}

extern "C" void kernel_launch(void* const* d_in, const int* in_sizes, int n_in,
                              void* d_out, int out_size, void* d_ws, size_t ws_size,
                              hipStream_t stream) {
    const float* x   = (const float*)d_in[0];
    const float* Wq  = (const float*)d_in[1];
    const float* Wk  = (const float*)d_in[2];
    // d_in[3] = Wv — dead code in the reference, skipped.
    const float* Wo  = (const float*)d_in[4];
    const float* W1  = (const float*)d_in[5];
    const float* b1  = (const float*)d_in[6];
    const float* W2  = (const float*)d_in[7];
    const float* b2  = (const float*)d_in[8];
    const float* g1  = (const float*)d_in[9];
    const float* be1 = (const float*)d_in[10];
    const float* g2  = (const float*)d_in[11];
    const float* be2 = (const float*)d_in[12];
    float* out = (float*)d_out;

    const int S = 8192, H = 768, MLP4 = 3072, H2 = 1536;

    char* ws = (char*)d_ws;
    u16* XB   = (u16*)ws;  ws += (size_t)S * H * 2;      // reused as CTXH
    u16* WQKT = (u16*)ws;  ws += (size_t)H2 * H * 2;
    u16* WOT  = (u16*)ws;  ws += (size_t)H * H * 2;      // k-permuted
    u16* W1T  = (u16*)ws;  ws += (size_t)H * MLP4 * 2;
    u16* W2T  = (u16*)ws;  ws += (size_t)H * MLP4 * 2;
    u16* QKB  = (u16*)ws;  ws += (size_t)S * H2 * 2;     // Q (log2-prescaled) | K, row-major
    u16* KH   = (u16*)ws;  ws += (size_t)S * H * 2;      // K head-major
    float* Y  = (float*)ws; ws += (size_t)S * H * 4;
    u16* HB   = (u16*)ws;  ws += (size_t)S * MLP4 * 2;

    u16* CTXH = XB;          // after QK gemm, XB is dead
    u16* X1B  = QKB;         // Q half, dead after attention
    u16* KHT  = HB;          // HB dead until W1 gemm; holds K transposed (12.6 MB < 50 MB)
    float* WoP = (float*)HB; // Wo K-split partial (25.2 MB); KHT dead after attention,
                             // HB rewritten by W1 only after LN1 consumes WoP
    float* Y1 = (float*)QKB; // QKB (25.2 MB) dead after W1 gemm; W2 K-split partial (exact fit)

    // 1. fused prep: x cast + all weight transposes
    prep_k<<<4608, 256, 0, stream>>>(x, Wq, Wk, Wo, W1, W2, XB, WQKT, WOT, W1T, W2T);

    // 2. [Q|K] = X [Wq|Wk]  (coalesced row-major out; Q half prescaled by 0.125*log2e)
    gemm_bt_k<4, 128><<<12 * 64, 256, 0, stream>>>(XB, WQKT, S, H2, H, 12, nullptr, QKB, nullptr, nullptr);

    // 3. attention (K repacked head-major + transposed; ctx stays head-major in CTXH)
    head_pack_k<<<dim3(64, 8), 256, 0, stream>>>(QKB + H, H2, KH, KHT);
    attention_k<<<dim3(16, 96), 256, 0, stream>>>(QKB, H2, KH, KHT, CTXH);

    // 4. y = x + ctx Wo ; x1 = LN1(y) + bf16 copy
    //    Wo K-split 2x: kp0 -> Y (resid+acc, heads 0-5), kp1 -> WoP (partial, heads 6-11);
    //    NS=3 (36 KB LDS), grid 6/CU; LN1 fuses Y+WoP.
    gemm_bt_k<1, 64, true, 3, true><<<2 * 6 * 128, 256, 0, stream>>>(CTXH, WOT, S, H, H, 6, Y, (u16*)WoP, x, nullptr);
    layernorm_k<<<S, 256, 0, stream>>>(Y, Y, X1B, g1, be1, WoP);

    // 5. h = gelu(x1 W1 + b1) ; y2 = x1 + h W2 + b2 ; out = LN2(y2)
    //    W2 K-split 2x: K [0,1536) -> Y (EPI3), [1536,3072) -> Y1 (partial);
    //    NS=3 (36 KB LDS -> 4 blocks/CU, grid 6/CU); LN2 fuses the Y+Y1 reduction.
    gemm_bt_k<2, 128><<<24 * 64, 256, 0, stream>>>(X1B, W1T, S, MLP4, H, 24, nullptr, HB, nullptr, b1);
    gemm_bt_k<3, 64, false, 3, true><<<2 * 6 * 128, 256, 0, stream>>>(HB, W2T, S, H, MLP4, 6, Y, (u16*)Y1, Y, b2);
    layernorm_k<<<S, 256, 0, stream>>>(Y, out, nullptr, g2, be2, Y1);
}

// Round 9
// 411.345 us; speedup vs baseline: 1.0187x; 1.0187x over previous
//
#include <hip/hip_runtime.h>
#include <math.h>

typedef unsigned short u16;
typedef unsigned int u32;
typedef short bf16x8 __attribute__((ext_vector_type(8)));
typedef float f32x4 __attribute__((ext_vector_type(4)));

#define MFMA(a, b, c) __builtin_amdgcn_mfma_f32_16x16x32_bf16((a), (b), (c), 0, 0, 0)

// async global->LDS, 16B per lane; LDS dest = wave-uniform base + lane*16
#define GLOAD_LDS16(g, l)                                                              \
    __builtin_amdgcn_global_load_lds((const __attribute__((address_space(1))) void*)(g), \
                                     (__attribute__((address_space(3))) void*)(l), 16, 0, 0)

__device__ __forceinline__ u16 f2bf(float f) {
    u32 u = __float_as_uint(f);
    u32 r = (u + 0x7fffu + ((u >> 16) & 1u)) >> 16;
    return (u16)r;
}

__device__ __forceinline__ u16 f2bf_trunc(float f) {  // truncating bf16 (1 VALU op)
    return (u16)(__float_as_uint(f) >> 16);
}

// tanh-form GELU via native exp/rcp
__device__ __forceinline__ float fast_gelu(float z) {
    float u = fminf(1.5957691216f * z * (1.0f + 0.044715f * z * z), 80.0f);
    float e = __expf(u);
    float r = __builtin_amdgcn_rcpf(e + 1.0f);
    return z * e * r;
}

// ================= fused prep: x cast + all weight transposes, one dispatch =================
__device__ void dev_xcast(const float* __restrict__ in, u16* __restrict__ out, int blk) {
    size_t i = ((size_t)blk * 256 + threadIdx.x) * 8;
    const float4* p = reinterpret_cast<const float4*>(in + i);
    float4 a = p[0], b = p[1];
    union { u16 u[8]; uint4 v; } o;
    o.u[0] = f2bf(a.x); o.u[1] = f2bf(a.y); o.u[2] = f2bf(a.z); o.u[3] = f2bf(a.w);
    o.u[4] = f2bf(b.x); o.u[5] = f2bf(b.y); o.u[6] = f2bf(b.z); o.u[7] = f2bf(b.w);
    *reinterpret_cast<uint4*>(out + i) = o.v;
}

__device__ void dev_transpose(const float* __restrict__ in, u16* __restrict__ out,
                              int K, int N, int bx, int by, float* tile /* [64][65] */) {
    int k0 = by * 64, n0 = bx * 64;
    int t = threadIdx.x;
    for (int p = 0; p < 16; p++) {
        int idx = t + p * 256;
        int r = idx >> 6, c = idx & 63;
        tile[r * 65 + c] = in[(size_t)(k0 + r) * N + n0 + c];
    }
    __syncthreads();
    for (int p = 0; p < 16; p++) {
        int idx = t + p * 256;
        int nr = idx >> 6, nc = idx & 63;
        out[(size_t)(n0 + nr) * K + k0 + nc] = f2bf(tile[nc * 65 + nr]);
    }
}

// Wo transpose with k-permute: out[col][n*64+d] = Wo[d*12+n][col]
__device__ void dev_wo(const float* __restrict__ in, u16* __restrict__ out,
                       int bx, int by, float* tile /* [96][65] */) {
    int k0 = by * 96, n0 = bx * 64;
    int t = threadIdx.x;
    for (int p = 0; p < 24; p++) {
        int idx = t + p * 256;
        int r = idx >> 6, c = idx & 63;
        tile[r * 65 + c] = in[(size_t)(k0 + r) * 768 + n0 + c];
    }
    __syncthreads();
    for (int p = 0; p < 3; p++) {
        int idx = t + p * 256;  // (col c)*12 + n
        int c = idx / 12, n = idx % 12;
        union { u16 u[8]; uint4 v; } o;
        for (int j = 0; j < 8; j++) o.u[j] = f2bf(tile[(j * 12 + n) * 65 + c]);
        *reinterpret_cast<uint4*>(&out[(size_t)(n0 + c) * 768 + n * 64 + by * 8]) = o.v;
    }
}

__global__ __launch_bounds__(256) void prep_k(const float* __restrict__ x,
                                              const float* __restrict__ Wq,
                                              const float* __restrict__ Wk,
                                              const float* __restrict__ Wo,
                                              const float* __restrict__ W1,
                                              const float* __restrict__ W2,
                                              u16* __restrict__ XB,
                                              u16* __restrict__ WQKT,
                                              u16* __restrict__ WOT,
                                              u16* __restrict__ W1T,
                                              u16* __restrict__ W2T) {
    __shared__ float tile[96 * 65];
    int bid = blockIdx.x;
    if (bid < 3072) {
        dev_xcast(x, XB, bid);
    } else if (bid < 3216) {
        int b = bid - 3072; dev_transpose(Wq, WQKT, 768, 768, b % 12, b / 12, tile);
    } else if (bid < 3360) {
        int b = bid - 3216; dev_transpose(Wk, WQKT + (size_t)768 * 768, 768, 768, b % 12, b / 12, tile);
    } else if (bid < 3456) {
        int b = bid - 3360; dev_wo(Wo, WOT, b % 12, b / 12, tile);
    } else if (bid < 4032) {
        int b = bid - 3456; dev_transpose(W1, W1T, 768, 3072, b % 48, b / 48, tile);
    } else {
        int b = bid - 4032; dev_transpose(W2, W2T, 3072, 768, b % 12, b / 12, tile);
    }
}

// ---------------- head pack: in (S x ld, col base pre-offset) -> KH (96 x 1024 x 64) ----------------
// Also emits KHT (96 x 64 x 1024): KHT[head][d][m] = K[b][m][d*12+n], so the attention
// kernel can stage its transposed K tile with vector loads instead of 16 scalar LDS writes.
__global__ __launch_bounds__(256) void head_pack_k(const u16* __restrict__ in, int ld,
                                                   u16* __restrict__ out,
                                                   u16* __restrict__ outT) {
    __shared__ u16 tile[16 * 768];
    int b = blockIdx.y;
    int l0 = blockIdx.x * 16;
    int t = threadIdx.x;
    for (int p = 0; p < 6; p++) {
        int c = t + p * 256;
        int li = c / 96, dc = c % 96;
        *reinterpret_cast<uint4*>(&tile[li * 768 + dc * 8]) =
            *reinterpret_cast<const uint4*>(&in[(size_t)(b * 1024 + l0 + li) * ld + dc * 8]);
    }
    __syncthreads();
    for (int p = 0; p < 6; p++) {
        int c = t + p * 256;
        int n = c >> 7, rem = c & 127, li = rem >> 3, k8 = rem & 7;
        union { u16 u[8]; uint4 v; } o;
        for (int j = 0; j < 8; j++) o.u[j] = tile[li * 768 + (k8 * 8 + j) * 12 + n];
        *reinterpret_cast<uint4*>(&out[(size_t)((b * 12 + n) * 1024 + l0 + li) * 64 + k8 * 8]) = o.v;
    }
    // transposed copy: 6 passes x 256 threads cover 12 heads x 64 d x 2 halves (8 m each)
    for (int p = 0; p < 6; p++) {
        int c = t + p * 256;                 // 0..1535
        int n = c >> 7;                      // head 0..11
        int rem = c & 127;
        int d = rem >> 1;                    // 0..63
        int half = rem & 1;                  // m-offset 0 or 8
        union { u16 u[8]; uint4 v; } o;
        for (int j = 0; j < 8; j++) o.u[j] = tile[(half * 8 + j) * 768 + d * 12 + n];
        *reinterpret_cast<uint4*>(
            &outT[((size_t)(b * 12 + n) * 64 + d) * 1024 + l0 + half * 8]) = o.v;
    }
}

// ---------------- GEMM: C(MxN) = A(MxK bf16) @ BT(NxK bf16)^T ----------------
// TM x 128 tile, NS-stage pipeline, ONE raw s_barrier per K-step, counted vmcnt (never 0
// except NS=2). K-loop unrolled in groups of NS (compile-time stage indices).
// XCD swizzle: column-blocks sharing an A-stripe -> same XCD.
// AH: A is CTXH [b*12+n][l][64], logical k = n*64+d (TM=64; BT rows permuted).
// KSPLIT: grid doubled; second half computes K-range [K/2,K) into outF2 (=outB as float*),
//         first half does the full epilogue on K-range [0,K/2). Reduction fused into next LN.
// EPI 1: outF = resid + acc;  2: outB = bf16(gelu(acc + bias[col]));
// EPI 3: outF = resid + acc + bias[col];
// EPI 4: outB = bf16(acc * (col<768 ? 0.125*log2e : 1))  [QK proj; Q in log2-domain]
template <int EPI, int TM, bool AH = false, int NSO = 0, bool KSPLIT = false>
__global__ __launch_bounds__(256) void gemm_bt_k(const u16* __restrict__ A,
                                                 const u16* __restrict__ BT,
                                                 int M, int N, int K, int NBX,
                                                 float* __restrict__ outF,
                                                 u16* __restrict__ outB,
                                                 const float* __restrict__ resid,
                                                 const float* __restrict__ bias) {
    constexpr int MI = TM / 32;
    constexpr int NS = NSO ? NSO : ((TM == 64) ? 4 : 3);
    constexpr int LPS = (TM == 128) ? 4 : 3;   // loads per K-step per thread
    constexpr int VC = LPS * (NS - 2);         // counted vmcnt at the wait point
    __shared__ __align__(16) u16 As[NS][TM * 32];
    __shared__ __align__(16) u16 Bs[NS][128 * 32];

    int L = blockIdx.x;
    int kp = 0;
    if constexpr (KSPLIT) {
        int half = gridDim.x >> 1;
        if (L >= half) { kp = 1; L -= half; }
    }
    int bx = (L >> 3) % NBX;
    int by = (L / (8 * NBX)) * 8 + (L & 7);
    int m0 = by * TM, n0 = bx * 128;

    int t = threadIdx.x;
    int wave = t >> 6, lane = t & 63;
    int wr = (wave >> 1) * (TM / 2), wc = (wave & 1) * 64;
    int ln = lane & 15, quad = lane >> 4;
    int sw = quad ^ ((ln >> 1) & 3);

    int e0 = t, e1 = t + 256;
    int r0 = e0 >> 2, c0 = (e0 & 3) ^ ((r0 >> 1) & 3);
    int r1 = e1 >> 2, c1 = (e1 & 3) ^ ((r1 >> 1) & 3);
    int kofs = 0;
    if constexpr (KSPLIT) kofs = kp * (K >> 1);
    int ahk = 0;  // AH: col8 offset for the K-split upper half (K/16 col8 groups)
    if constexpr (KSPLIT && AH) ahk = kp * (K >> 4);
    const u16* A0 = A + (size_t)(m0 + r0) * K + kofs + c0 * 8;
    const u16* A1 = A + (size_t)(m0 + r1) * K + kofs + c1 * 8;  // TM==128 only
    const u16* B0 = BT + (size_t)(n0 + r0) * K + kofs + c0 * 8;
    const u16* B1 = BT + (size_t)(n0 + r1) * K + kofs + c1 * 8;
    const u16* Abase = nullptr;
    if constexpr (AH) {
        int m = m0 + r0;
        Abase = A + ((size_t)(m >> 10) * 12288 + (m & 1023)) * 64;
    }

    int nk = K >> 5;  // multiple of NS for all shapes here
    if constexpr (KSPLIT) nk >>= 1;

    f32x4 acc[MI][4];
    for (int i = 0; i < MI; i++)
        for (int j = 0; j < 4; j++)
            for (int r = 0; r < 4; r++) acc[i][j][r] = 0.0f;

    for (int s = 0; s < NS - 1; s++) {
        if constexpr (AH) {
            int col8 = ahk + s * 4 + c0;
            GLOAD_LDS16(Abase + (col8 >> 3) * 65536 + (col8 & 7) * 8, &As[s][e0 * 8]);
        } else {
            GLOAD_LDS16(A0 + s * 32, &As[s][e0 * 8]);
            if constexpr (TM == 128) GLOAD_LDS16(A1 + s * 32, &As[s][e1 * 8]);
        }
        GLOAD_LDS16(B0 + s * 32, &Bs[s][e0 * 8]);
        GLOAD_LDS16(B1 + s * 32, &Bs[s][e1 * 8]);
    }

    for (int kb = 0; kb < nk; kb += NS) {
#pragma unroll
        for (int s = 0; s < NS; s++) {
            int k = kb + s;
            if constexpr (VC == 6)      asm volatile("s_waitcnt vmcnt(6)" ::: "memory");
            else if constexpr (VC == 4) asm volatile("s_waitcnt vmcnt(4)" ::: "memory");
            else if constexpr (VC == 3) asm volatile("s_waitcnt vmcnt(3)" ::: "memory");
            else                        asm volatile("s_waitcnt vmcnt(0)" ::: "memory");
            asm volatile("s_barrier" ::: "memory");
            {
                int ks = k + NS - 1 < nk ? k + NS - 1 : nk - 1;  // clamped: uniform in-flight count
                int stage = (s + NS - 1) % NS;  // s constant under unroll -> folds
                if constexpr (AH) {
                    int col8 = ahk + ks * 4 + c0;
                    GLOAD_LDS16(Abase + (col8 >> 3) * 65536 + (col8 & 7) * 8, &As[stage][e0 * 8]);
                } else {
                    GLOAD_LDS16(A0 + ks * 32, &As[stage][e0 * 8]);
                    if constexpr (TM == 128) GLOAD_LDS16(A1 + ks * 32, &As[stage][e1 * 8]);
                }
                GLOAD_LDS16(B0 + ks * 32, &Bs[stage][e0 * 8]);
                GLOAD_LDS16(B1 + ks * 32, &Bs[stage][e1 * 8]);
            }
            const u16* as = As[s];
            const u16* bs = Bs[s];
            bf16x8 afr[MI], bfr[4];
            for (int i = 0; i < MI; i++)
                afr[i] = *reinterpret_cast<const bf16x8*>(&as[(wr + i * 16 + ln) * 32 + sw * 8]);
            for (int j = 0; j < 4; j++)
                bfr[j] = *reinterpret_cast<const bf16x8*>(&bs[(wc + j * 16 + ln) * 32 + sw * 8]);
            for (int i = 0; i < MI; i++)
                for (int j = 0; j < 4; j++)
                    acc[i][j] = MFMA(afr[i], bfr[j], acc[i][j]);
        }
    }

    for (int i = 0; i < MI; i++) {
        for (int j = 0; j < 4; j++) {
            int col = n0 + wc + j * 16 + ln;
            for (int r = 0; r < 4; r++) {
                int row = m0 + wr + i * 16 + quad * 4 + r;
                size_t idx = (size_t)row * N + col;
                float v = acc[i][j][r];
                if constexpr (EPI == 1) {
                    if constexpr (KSPLIT) {
                        if (kp == 0) outF[idx] = resid[idx] + v;
                        else reinterpret_cast<float*>(outB)[idx] = v;
                    } else {
                        outF[idx] = resid[idx] + v;
                    }
                } else if constexpr (EPI == 2) {
                    outB[idx] = f2bf(fast_gelu(v + bias[col]));
                } else if constexpr (EPI == 3) {
                    if constexpr (KSPLIT) {
                        if (kp == 0) outF[idx] = resid[idx] + v + bias[col];
                        else reinterpret_cast<float*>(outB)[idx] = v;
                    } else {
                        outF[idx] = resid[idx] + v + bias[col];
                    }
                } else {
                    // 0.125 * log2(e): Q scores land in log2 domain for exp2 softmax
                    outB[idx] = f2bf(col < 768 ? v * 0.18033688011112042f : v);
                }
            }
        }
    }
}

// ---------------- flash-style attention (ctx = softmax @ K), Q prescaled to log2 domain ----------------
// QB row-major (ldq), KH head-major, KHT head-major-transposed [head][d][m].
// p = exp2(st) (no max, no clamp: st ~ N(0,1.44)).
// P-tile: plain stride 72 (r5-measured fewer conflicts than XOR-64). P stored truncated.
// KsT staged with 2 vector loads + 2 ds_write_b128 (was: 16 scalar ds_write_b16).
__global__ __launch_bounds__(256) void attention_k(const u16* __restrict__ QB, int ldq,
                                                   const u16* __restrict__ KH,
                                                   const u16* __restrict__ KHT,
                                                   u16* __restrict__ CTXH) {
    __shared__ __align__(16) u16 Ks[64 * 72];   // [m'][d]
    __shared__ __align__(16) u16 KsT[64 * 72];  // [d][m']
    __shared__ __align__(16) u16 Pl[4][16 * 72];
    int bh = blockIdx.y;
    int b = bh / 12, n = bh % 12;
    int l0 = blockIdx.x * 64;
    int t = threadIdx.x, wave = t >> 6, lane = t & 63;
    int ln = lane & 15, quad = lane >> 4;
    int lw = l0 + wave * 16;

    // Q A-fragments (strided gather, once per block); Q already scaled by 0.125*log2e
    bf16x8 a0, a1;
    {
        union { u16 u[8]; bf16x8 v; } q0, q1;
        const u16* qrow = QB + (size_t)(b * 1024 + lw + ln) * ldq + n;
        for (int j = 0; j < 8; j++) {
            q0.u[j] = qrow[(quad * 8 + j) * 12];
            q1.u[j] = qrow[(32 + quad * 8 + j) * 12];
        }
        a0 = q0.v; a1 = q1.v;
    }

    f32x4 o[4];
    for (int dt = 0; dt < 4; dt++)
        for (int r = 0; r < 4; r++) o[dt][r] = 0.0f;
    float lst[4];
    for (int r = 0; r < 4; r++) lst[r] = 0.0f;

    const u16* Kbase  = KH  + (size_t)bh * 65536;
    const u16* KTbase = KHT + (size_t)bh * 65536;  // [d][m], 64 rows x 1024
    int mi = t & 63, ds = (t >> 6) * 16;

    uint4 kva = *reinterpret_cast<const uint4*>(&Kbase[(size_t)mi * 64 + ds]);
    uint4 kvb = *reinterpret_cast<const uint4*>(&Kbase[(size_t)mi * 64 + ds + 8]);
    uint4 kta = *reinterpret_cast<const uint4*>(&KTbase[(size_t)mi * 1024 + ds]);
    uint4 ktb = *reinterpret_cast<const uint4*>(&KTbase[(size_t)mi * 1024 + ds + 8]);

    for (int mb = 0; mb < 16; mb++) {
        __syncthreads();
        *reinterpret_cast<uint4*>(&Ks[mi * 72 + ds]) = kva;
        *reinterpret_cast<uint4*>(&Ks[mi * 72 + ds + 8]) = kvb;
        *reinterpret_cast<uint4*>(&KsT[mi * 72 + ds]) = kta;
        *reinterpret_cast<uint4*>(&KsT[mi * 72 + ds + 8]) = ktb;
        __syncthreads();

        {
            int mnext = (mb + 1 < 16 ? mb + 1 : 15) * 64;
            kva = *reinterpret_cast<const uint4*>(&Kbase[(size_t)(mnext + mi) * 64 + ds]);
            kvb = *reinterpret_cast<const uint4*>(&Kbase[(size_t)(mnext + mi) * 64 + ds + 8]);
            kta = *reinterpret_cast<const uint4*>(&KTbase[(size_t)mi * 1024 + mnext + ds]);
            ktb = *reinterpret_cast<const uint4*>(&KTbase[(size_t)mi * 1024 + mnext + ds + 8]);
        }

        f32x4 st[4];
        for (int nt = 0; nt < 4; nt++) {
            bf16x8 bk0 = *reinterpret_cast<bf16x8*>(&Ks[(nt * 16 + ln) * 72 + quad * 8]);
            bf16x8 bk1 = *reinterpret_cast<bf16x8*>(&Ks[(nt * 16 + ln) * 72 + 32 + quad * 8]);
            f32x4 z;
            for (int r = 0; r < 4; r++) z[r] = 0.0f;
            z = MFMA(a0, bk0, z);
            st[nt] = MFMA(a1, bk1, z);
        }

        // softmax numerator: p = exp2(st) (st already includes 1/8 * log2e); no max, no clamp
        for (int r = 0; r < 4; r++) {
            int row = quad * 4 + r;
            float psum = 0.0f;
            for (int nt = 0; nt < 4; nt++) {
                float p = exp2f(st[nt][r]);
                psum += p;
                Pl[wave][row * 72 + nt * 16 + ln] = f2bf_trunc(p);
            }
            lst[r] += psum;
        }

        // PV: O += P(16x64) @ K(64x64)   (Pl wave-private: no barrier)
        bf16x8 pf0 = *reinterpret_cast<bf16x8*>(&Pl[wave][ln * 72 + quad * 8]);
        bf16x8 pf1 = *reinterpret_cast<bf16x8*>(&Pl[wave][ln * 72 + 32 + quad * 8]);
        for (int dt = 0; dt < 4; dt++) {
            bf16x8 bk0 = *reinterpret_cast<bf16x8*>(&KsT[(dt * 16 + ln) * 72 + quad * 8]);
            bf16x8 bk1 = *reinterpret_cast<bf16x8*>(&KsT[(dt * 16 + ln) * 72 + 32 + quad * 8]);
            o[dt] = MFMA(pf0, bk0, o[dt]);
            o[dt] = MFMA(pf1, bk1, o[dt]);
        }
    }

    for (int r = 0; r < 4; r++)
        for (int off = 1; off < 16; off <<= 1) lst[r] += __shfl_xor(lst[r], off, 64);

    u16* out = CTXH + (size_t)bh * 65536;
    for (int r = 0; r < 4; r++) {
        float inv = 1.0f / lst[r];
        int row = lw + quad * 4 + r;
        for (int dt = 0; dt < 4; dt++)
            out[(size_t)row * 64 + dt * 16 + ln] = f2bf(o[dt][r] * inv);
    }
}

// ---------------- layernorm over 768, one block per row; optional second input (K-split reduce) ----------------
__global__ __launch_bounds__(256) void layernorm_k(const float* __restrict__ in,
                                                   float* __restrict__ outF,
                                                   u16* __restrict__ outB,
                                                   const float* __restrict__ g,
                                                   const float* __restrict__ be,
                                                   const float* __restrict__ in2) {
    __shared__ float red[8];
    int row = blockIdx.x;
    int t = threadIdx.x;
    const float* p = in + (size_t)row * 768;
    float v0 = p[t], v1 = p[t + 256], v2 = p[t + 512];
    if (in2) {
        const float* p2 = in2 + (size_t)row * 768;
        v0 += p2[t]; v1 += p2[t + 256]; v2 += p2[t + 512];
    }
    float s = v0 + v1 + v2;
    float ss = v0 * v0 + v1 * v1 + v2 * v2;
    for (int off = 32; off >= 1; off >>= 1) {
        s += __shfl_xor(s, off, 64);
        ss += __shfl_xor(ss, off, 64);
    }
    int wave = t >> 6, lane = t & 63;
    if (lane == 0) { red[wave] = s; red[4 + wave] = ss; }
    __syncthreads();
    float S = red[0] + red[1] + red[2] + red[3];
    float SS = red[4] + red[5] + red[6] + red[7];
    float mean = S * (1.0f / 768.0f);
    float var = SS * (1.0f / 768.0f) - mean * mean;
    float rstd = rsqrtf(var + 1e-5f);
    float o0 = (v0 - mean) * rstd * g[t] + be[t];
    float o1 = (v1 - mean) * rstd * g[t + 256] + be[t + 256];
    float o2 = (v2 - mean) * rstd * g[t + 512] + be[t + 512];
    float* q = outF + (size_t)row * 768;
    q[t] = o0; q[t + 256] = o1; q[t + 512] = o2;
    if (outB) {
        u16* qb = outB + (size_t)row * 768;
        qb[t] = f2bf(o0); qb[t + 256] = f2bf(o1); qb[t + 512] = f2bf(o2);
    }
}

extern "C" void kernel_launch(void* const* d_in, const int* in_sizes, int n_in,
                              void* d_out, int out_size, void* d_ws, size_t ws_size,
                              hipStream_t stream) {
    const float* x   = (const float*)d_in[0];
    const float* Wq  = (const float*)d_in[1];
    const float* Wk  = (const float*)d_in[2];
    // d_in[3] = Wv — dead code in the reference, skipped.
    const float* Wo  = (const float*)d_in[4];
    const float* W1  = (const float*)d_in[5];
    const float* b1  = (const float*)d_in[6];
    const float* W2  = (const float*)d_in[7];
    const float* b2  = (const float*)d_in[8];
    const float* g1  = (const float*)d_in[9];
    const float* be1 = (const float*)d_in[10];
    const float* g2  = (const float*)d_in[11];
    const float* be2 = (const float*)d_in[12];
    float* out = (float*)d_out;

    const int S = 8192, H = 768, MLP4 = 3072, H2 = 1536;

    char* ws = (char*)d_ws;
    u16* XB   = (u16*)ws;  ws += (size_t)S * H * 2;      // reused as CTXH
    u16* WQKT = (u16*)ws;  ws += (size_t)H2 * H * 2;
    u16* WOT  = (u16*)ws;  ws += (size_t)H * H * 2;      // k-permuted
    u16* W1T  = (u16*)ws;  ws += (size_t)H * MLP4 * 2;
    u16* W2T  = (u16*)ws;  ws += (size_t)H * MLP4 * 2;
    u16* QKB  = (u16*)ws;  ws += (size_t)S * H2 * 2;     // Q (log2-prescaled) | K, row-major
    u16* KH   = (u16*)ws;  ws += (size_t)S * H * 2;      // K head-major
    float* Y  = (float*)ws; ws += (size_t)S * H * 4;
    u16* HB   = (u16*)ws;  ws += (size_t)S * MLP4 * 2;

    u16* CTXH = XB;          // after QK gemm, XB is dead
    u16* X1B  = QKB;         // Q half, dead after attention
    u16* KHT  = HB;          // HB dead until W1 gemm; holds K transposed (12.6 MB < 50 MB)
    float* Y1 = (float*)QKB; // QKB (25.2 MB) dead after W1 gemm; W2 K-split partial (exact fit)

    // 1. fused prep: x cast + all weight transposes
    prep_k<<<4608, 256, 0, stream>>>(x, Wq, Wk, Wo, W1, W2, XB, WQKT, WOT, W1T, W2T);

    // 2. [Q|K] = X [Wq|Wk]  (coalesced row-major out; Q half prescaled by 0.125*log2e)
    gemm_bt_k<4, 128><<<12 * 64, 256, 0, stream>>>(XB, WQKT, S, H2, H, 12, nullptr, QKB, nullptr, nullptr);

    // 3. attention (K repacked head-major + transposed; ctx stays head-major in CTXH)
    head_pack_k<<<dim3(64, 8), 256, 0, stream>>>(QKB + H, H2, KH, KHT);
    attention_k<<<dim3(16, 96), 256, 0, stream>>>(QKB, H2, KH, KHT, CTXH);

    // 4. y = x + ctx Wo ; x1 = LN1(y) in-place + bf16 copy  (round-3 config: unsplit, NS=4)
    gemm_bt_k<1, 64, true><<<6 * 128, 256, 0, stream>>>(CTXH, WOT, S, H, H, 6, Y, nullptr, x, nullptr);
    layernorm_k<<<S, 256, 0, stream>>>(Y, Y, X1B, g1, be1, nullptr);

    // 5. h = gelu(x1 W1 + b1) ; y2 = x1 + h W2 + b2 ; out = LN2(y2)
    //    W2: TM=128 fat tile + K-split 2x -> grid 768 = exactly 3 blocks/CU (48 KB LDS),
    //    48 K-steps x 16 MFMA/wave (was 96 x 8). kp0 -> Y (EPI3), kp1 -> Y1; LN2 fuses Y+Y1.
    gemm_bt_k<2, 128><<<24 * 64, 256, 0, stream>>>(X1B, W1T, S, MLP4, H, 24, nullptr, HB, nullptr, b1);
    gemm_bt_k<3, 128, false, 0, true><<<2 * 6 * 64, 256, 0, stream>>>(HB, W2T, S, H, MLP4, 6, Y, (u16*)Y1, Y, b2);
    layernorm_k<<<S, 256, 0, stream>>>(Y, out, nullptr, g2, be2, Y1);
}

// Round 13
// 395.863 us; speedup vs baseline: 1.0585x; 1.0391x over previous
//
#include <hip/hip_runtime.h>
#include <math.h>

typedef unsigned short u16;
typedef unsigned int u32;
typedef short bf16x8 __attribute__((ext_vector_type(8)));
typedef float f32x4 __attribute__((ext_vector_type(4)));

#define MFMA(a, b, c) __builtin_amdgcn_mfma_f32_16x16x32_bf16((a), (b), (c), 0, 0, 0)

// async global->LDS, 16B per lane; LDS dest = wave-uniform base + lane*16
#define GLOAD_LDS16(g, l)                                                              \
    __builtin_amdgcn_global_load_lds((const __attribute__((address_space(1))) void*)(g), \
                                     (__attribute__((address_space(3))) void*)(l), 16, 0, 0)

__device__ __forceinline__ u16 f2bf(float f) {
    u32 u = __float_as_uint(f);
    u32 r = (u + 0x7fffu + ((u >> 16) & 1u)) >> 16;
    return (u16)r;
}

__device__ __forceinline__ u16 f2bf_trunc(float f) {  // truncating bf16 (1 VALU op)
    return (u16)(__float_as_uint(f) >> 16);
}

// tanh-form GELU via native exp/rcp
__device__ __forceinline__ float fast_gelu(float z) {
    float u = fminf(1.5957691216f * z * (1.0f + 0.044715f * z * z), 80.0f);
    float e = __expf(u);
    float r = __builtin_amdgcn_rcpf(e + 1.0f);
    return z * e * r;
}

// ================= fused prep: x cast + all weight transposes, one dispatch =================
__device__ void dev_xcast(const float* __restrict__ in, u16* __restrict__ out, int blk) {
    size_t i = ((size_t)blk * 256 + threadIdx.x) * 8;
    const float4* p = reinterpret_cast<const float4*>(in + i);
    float4 a = p[0], b = p[1];
    union { u16 u[8]; uint4 v; } o;
    o.u[0] = f2bf(a.x); o.u[1] = f2bf(a.y); o.u[2] = f2bf(a.z); o.u[3] = f2bf(a.w);
    o.u[4] = f2bf(b.x); o.u[5] = f2bf(b.y); o.u[6] = f2bf(b.z); o.u[7] = f2bf(b.w);
    *reinterpret_cast<uint4*>(out + i) = o.v;
}

__device__ void dev_transpose(const float* __restrict__ in, u16* __restrict__ out,
                              int K, int N, int bx, int by, float* tile /* [64][65] */) {
    int k0 = by * 64, n0 = bx * 64;
    int t = threadIdx.x;
    for (int p = 0; p < 16; p++) {
        int idx = t + p * 256;
        int r = idx >> 6, c = idx & 63;
        tile[r * 65 + c] = in[(size_t)(k0 + r) * N + n0 + c];
    }
    __syncthreads();
    for (int p = 0; p < 16; p++) {
        int idx = t + p * 256;
        int nr = idx >> 6, nc = idx & 63;
        out[(size_t)(n0 + nr) * K + k0 + nc] = f2bf(tile[nc * 65 + nr]);
    }
}

// Wo transpose with k-permute: out[col][n*64+d] = Wo[d*12+n][col]
__device__ void dev_wo(const float* __restrict__ in, u16* __restrict__ out,
                       int bx, int by, float* tile /* [96][65] */) {
    int k0 = by * 96, n0 = bx * 64;
    int t = threadIdx.x;
    for (int p = 0; p < 24; p++) {
        int idx = t + p * 256;
        int r = idx >> 6, c = idx & 63;
        tile[r * 65 + c] = in[(size_t)(k0 + r) * 768 + n0 + c];
    }
    __syncthreads();
    for (int p = 0; p < 3; p++) {
        int idx = t + p * 256;  // (col c)*12 + n
        int c = idx / 12, n = idx % 12;
        union { u16 u[8]; uint4 v; } o;
        for (int j = 0; j < 8; j++) o.u[j] = f2bf(tile[(j * 12 + n) * 65 + c]);
        *reinterpret_cast<uint4*>(&out[(size_t)(n0 + c) * 768 + n * 64 + by * 8]) = o.v;
    }
}

__global__ __launch_bounds__(256) void prep_k(const float* __restrict__ x,
                                              const float* __restrict__ Wq,
                                              const float* __restrict__ Wk,
                                              const float* __restrict__ Wo,
                                              const float* __restrict__ W1,
                                              const float* __restrict__ W2,
                                              u16* __restrict__ XB,
                                              u16* __restrict__ WQKT,
                                              u16* __restrict__ WOT,
                                              u16* __restrict__ W1T,
                                              u16* __restrict__ W2T) {
    __shared__ float tile[96 * 65];
    int bid = blockIdx.x;
    if (bid < 3072) {
        dev_xcast(x, XB, bid);
    } else if (bid < 3216) {
        int b = bid - 3072; dev_transpose(Wq, WQKT, 768, 768, b % 12, b / 12, tile);
    } else if (bid < 3360) {
        int b = bid - 3216; dev_transpose(Wk, WQKT + (size_t)768 * 768, 768, 768, b % 12, b / 12, tile);
    } else if (bid < 3456) {
        int b = bid - 3360; dev_wo(Wo, WOT, b % 12, b / 12, tile);
    } else if (bid < 4032) {
        int b = bid - 3456; dev_transpose(W1, W1T, 768, 3072, b % 48, b / 48, tile);
    } else {
        int b = bid - 4032; dev_transpose(W2, W2T, 3072, 768, b % 12, b / 12, tile);
    }
}

// ---------------- head pack: in (S x ld, col base pre-offset) -> KH (96 x 1024 x 64) ----------------
// Also emits KHT (96 x 64 x 1024): KHT[head][d][m] = K[b][m][d*12+n].
__global__ __launch_bounds__(256) void head_pack_k(const u16* __restrict__ in, int ld,
                                                   u16* __restrict__ out,
                                                   u16* __restrict__ outT) {
    __shared__ u16 tile[16 * 768];
    int b = blockIdx.y;
    int l0 = blockIdx.x * 16;
    int t = threadIdx.x;
    for (int p = 0; p < 6; p++) {
        int c = t + p * 256;
        int li = c / 96, dc = c % 96;
        *reinterpret_cast<uint4*>(&tile[li * 768 + dc * 8]) =
            *reinterpret_cast<const uint4*>(&in[(size_t)(b * 1024 + l0 + li) * ld + dc * 8]);
    }
    __syncthreads();
    for (int p = 0; p < 6; p++) {
        int c = t + p * 256;
        int n = c >> 7, rem = c & 127, li = rem >> 3, k8 = rem & 7;
        union { u16 u[8]; uint4 v; } o;
        for (int j = 0; j < 8; j++) o.u[j] = tile[li * 768 + (k8 * 8 + j) * 12 + n];
        *reinterpret_cast<uint4*>(&out[(size_t)((b * 12 + n) * 1024 + l0 + li) * 64 + k8 * 8]) = o.v;
    }
    // transposed copy: 6 passes x 256 threads cover 12 heads x 64 d x 2 halves (8 m each)
    for (int p = 0; p < 6; p++) {
        int c = t + p * 256;                 // 0..1535
        int n = c >> 7;                      // head 0..11
        int rem = c & 127;
        int d = rem >> 1;                    // 0..63
        int half = rem & 1;                  // m-offset 0 or 8
        union { u16 u[8]; uint4 v; } o;
        for (int j = 0; j < 8; j++) o.u[j] = tile[(half * 8 + j) * 768 + d * 12 + n];
        *reinterpret_cast<uint4*>(
            &outT[((size_t)(b * 12 + n) * 64 + d) * 1024 + l0 + half * 8]) = o.v;
    }
}

// ---------------- GEMM: C(MxN) = A(MxK bf16) @ BT(NxK bf16)^T ----------------
// TM x 128 tile, NS-stage pipeline, ONE raw s_barrier per K-step, counted vmcnt.
// NT=256: 4 waves (2x2, 64-col subtiles).  NT=512: 8 waves (2x4, 32-col subtiles) —
//   halves per-wave unified regs (~156 -> ~85) to move up an occupancy bracket
//   (2 -> 4 waves/SIMD; 8 -> 16 waves/CU) for the TM=128 shapes. [r9 counters: 156u -> Occ 16%]
// AH: A is CTXH [b*12+n][l][64], logical k = n*64+d (TM=64; BT rows permuted).
// KSPLIT kept for reference (unused this round).
// EPI 1: outF = resid + acc;  2: outB = bf16(gelu(acc + bias[col]));
// EPI 3: outF = resid + acc + bias[col];
// EPI 4: outB = bf16(acc * (col<768 ? 0.125*log2e : 1))  [QK proj; Q in log2-domain]
template <int EPI, int TM, bool AH = false, int NSO = 0, bool KSPLIT = false, int NT = 256>
__global__ __launch_bounds__(NT) void gemm_bt_k(const u16* __restrict__ A,
                                                const u16* __restrict__ BT,
                                                int M, int N, int K, int NBX,
                                                float* __restrict__ outF,
                                                u16* __restrict__ outB,
                                                const float* __restrict__ resid,
                                                const float* __restrict__ bias) {
    constexpr int NS = NSO ? NSO : ((TM == 64) ? 4 : 3);
    constexpr int WN = (NT == 512) ? 4 : 2;          // waves along N
    constexpr int MI = (TM / 2) / 16;                // A-frag repeats per wave
    constexpr int NJ = (128 / WN) / 16;              // B-frag repeats per wave
    constexpr int ALD = (TM == 128 && NT == 256) ? 2 : 1;  // A loads / thread / step
    constexpr int BLD = (NT == 256) ? 2 : 1;               // B loads / thread / step
    constexpr int LPS = ALD + BLD;
    constexpr int VC = LPS * (NS - 2);               // counted vmcnt at the wait point
    __shared__ __align__(16) u16 As[NS][TM * 32];
    __shared__ __align__(16) u16 Bs[NS][128 * 32];

    int L = blockIdx.x;
    int kp = 0;
    if constexpr (KSPLIT) {
        int half = gridDim.x >> 1;
        if (L >= half) { kp = 1; L -= half; }
    }
    int bx = (L >> 3) % NBX;
    int by = (L / (8 * NBX)) * 8 + (L & 7);
    int m0 = by * TM, n0 = bx * 128;

    int t = threadIdx.x;
    int wave = t >> 6, lane = t & 63;
    int wr = (wave / WN) * (TM / 2), wc = (wave % WN) * (128 / WN);
    int ln = lane & 15, quad = lane >> 4;
    int sw = quad ^ ((ln >> 1) & 3);

    int e0 = t, e1 = t + 256;                        // e1 only used when NT==256
    int r0 = e0 >> 2, c0 = (e0 & 3) ^ ((r0 >> 1) & 3);
    int r1 = e1 >> 2, c1 = (e1 & 3) ^ ((r1 >> 1) & 3);
    int kofs = 0;
    if constexpr (KSPLIT) kofs = kp * (K >> 1);
    int ahk = 0;
    if constexpr (KSPLIT && AH) ahk = kp * (K >> 4);
    const u16* A0 = A + (size_t)(m0 + r0) * K + kofs + c0 * 8;
    const u16* A1 = A + (size_t)(m0 + r1) * K + kofs + c1 * 8;  // ALD==2 only
    const u16* B0 = BT + (size_t)(n0 + r0) * K + kofs + c0 * 8;
    const u16* B1 = BT + (size_t)(n0 + r1) * K + kofs + c1 * 8; // BLD==2 only
    const u16* Abase = nullptr;
    if constexpr (AH) {
        int m = m0 + r0;
        Abase = A + ((size_t)(m >> 10) * 12288 + (m & 1023)) * 64;
    }

    int nk = K >> 5;
    if constexpr (KSPLIT) nk >>= 1;

    f32x4 acc[MI][NJ];
    for (int i = 0; i < MI; i++)
        for (int j = 0; j < NJ; j++)
            for (int r = 0; r < 4; r++) acc[i][j][r] = 0.0f;

    for (int s = 0; s < NS - 1; s++) {
        if constexpr (AH) {
            int col8 = ahk + s * 4 + c0;
            GLOAD_LDS16(Abase + (col8 >> 3) * 65536 + (col8 & 7) * 8, &As[s][e0 * 8]);
        } else {
            GLOAD_LDS16(A0 + s * 32, &As[s][e0 * 8]);
            if constexpr (ALD == 2) GLOAD_LDS16(A1 + s * 32, &As[s][e1 * 8]);
        }
        GLOAD_LDS16(B0 + s * 32, &Bs[s][e0 * 8]);
        if constexpr (BLD == 2) GLOAD_LDS16(B1 + s * 32, &Bs[s][e1 * 8]);
    }

    for (int kb = 0; kb < nk; kb += NS) {
#pragma unroll
        for (int s = 0; s < NS; s++) {
            int k = kb + s;
            if constexpr (VC == 6)      asm volatile("s_waitcnt vmcnt(6)" ::: "memory");
            else if constexpr (VC == 4) asm volatile("s_waitcnt vmcnt(4)" ::: "memory");
            else if constexpr (VC == 3) asm volatile("s_waitcnt vmcnt(3)" ::: "memory");
            else if constexpr (VC == 2) asm volatile("s_waitcnt vmcnt(2)" ::: "memory");
            else                        asm volatile("s_waitcnt vmcnt(0)" ::: "memory");
            asm volatile("s_barrier" ::: "memory");
            {
                int ks = k + NS - 1 < nk ? k + NS - 1 : nk - 1;  // clamped: uniform in-flight count
                int stage = (s + NS - 1) % NS;  // s constant under unroll -> folds
                if constexpr (AH) {
                    int col8 = ahk + ks * 4 + c0;
                    GLOAD_LDS16(Abase + (col8 >> 3) * 65536 + (col8 & 7) * 8, &As[stage][e0 * 8]);
                } else {
                    GLOAD_LDS16(A0 + ks * 32, &As[stage][e0 * 8]);
                    if constexpr (ALD == 2) GLOAD_LDS16(A1 + ks * 32, &As[stage][e1 * 8]);
                }
                GLOAD_LDS16(B0 + ks * 32, &Bs[stage][e0 * 8]);
                if constexpr (BLD == 2) GLOAD_LDS16(B1 + ks * 32, &Bs[stage][e1 * 8]);
            }
            const u16* as = As[s];
            const u16* bs = Bs[s];
            bf16x8 afr[MI], bfr[NJ];
            for (int i = 0; i < MI; i++)
                afr[i] = *reinterpret_cast<const bf16x8*>(&as[(wr + i * 16 + ln) * 32 + sw * 8]);
            for (int j = 0; j < NJ; j++)
                bfr[j] = *reinterpret_cast<const bf16x8*>(&bs[(wc + j * 16 + ln) * 32 + sw * 8]);
            for (int i = 0; i < MI; i++)
                for (int j = 0; j < NJ; j++)
                    acc[i][j] = MFMA(afr[i], bfr[j], acc[i][j]);
        }
    }

    for (int i = 0; i < MI; i++) {
        for (int j = 0; j < NJ; j++) {
            int col = n0 + wc + j * 16 + ln;
            for (int r = 0; r < 4; r++) {
                int row = m0 + wr + i * 16 + quad * 4 + r;
                size_t idx = (size_t)row * N + col;
                float v = acc[i][j][r];
                if constexpr (EPI == 1) {
                    if constexpr (KSPLIT) {
                        if (kp == 0) outF[idx] = resid[idx] + v;
                        else reinterpret_cast<float*>(outB)[idx] = v;
                    } else {
                        outF[idx] = resid[idx] + v;
                    }
                } else if constexpr (EPI == 2) {
                    outB[idx] = f2bf(fast_gelu(v + bias[col]));
                } else if constexpr (EPI == 3) {
                    if constexpr (KSPLIT) {
                        if (kp == 0) outF[idx] = resid[idx] + v + bias[col];
                        else reinterpret_cast<float*>(outB)[idx] = v;
                    } else {
                        outF[idx] = resid[idx] + v + bias[col];
                    }
                } else {
                    // 0.125 * log2(e): Q scores land in log2 domain for exp2 softmax
                    outB[idx] = f2bf(col < 768 ? v * 0.18033688011112042f : v);
                }
            }
        }
    }
}

// ---------------- flash-style attention (ctx = softmax @ K), Q prescaled to log2 domain ----------------
__global__ __launch_bounds__(256) void attention_k(const u16* __restrict__ QB, int ldq,
                                                   const u16* __restrict__ KH,
                                                   const u16* __restrict__ KHT,
                                                   u16* __restrict__ CTXH) {
    __shared__ __align__(16) u16 Ks[64 * 72];   // [m'][d]
    __shared__ __align__(16) u16 KsT[64 * 72];  // [d][m']
    __shared__ __align__(16) u16 Pl[4][16 * 72];
    int bh = blockIdx.y;
    int b = bh / 12, n = bh % 12;
    int l0 = blockIdx.x * 64;
    int t = threadIdx.x, wave = t >> 6, lane = t & 63;
    int ln = lane & 15, quad = lane >> 4;
    int lw = l0 + wave * 16;

    // Q A-fragments (strided gather, once per block); Q already scaled by 0.125*log2e
    bf16x8 a0, a1;
    {
        union { u16 u[8]; bf16x8 v; } q0, q1;
        const u16* qrow = QB + (size_t)(b * 1024 + lw + ln) * ldq + n;
        for (int j = 0; j < 8; j++) {
            q0.u[j] = qrow[(quad * 8 + j) * 12];
            q1.u[j] = qrow[(32 + quad * 8 + j) * 12];
        }
        a0 = q0.v; a1 = q1.v;
    }

    f32x4 o[4];
    for (int dt = 0; dt < 4; dt++)
        for (int r = 0; r < 4; r++) o[dt][r] = 0.0f;
    float lst[4];
    for (int r = 0; r < 4; r++) lst[r] = 0.0f;

    const u16* Kbase  = KH  + (size_t)bh * 65536;
    const u16* KTbase = KHT + (size_t)bh * 65536;  // [d][m], 64 rows x 1024
    int mi = t & 63, ds = (t >> 6) * 16;

    uint4 kva = *reinterpret_cast<const uint4*>(&Kbase[(size_t)mi * 64 + ds]);
    uint4 kvb = *reinterpret_cast<const uint4*>(&Kbase[(size_t)mi * 64 + ds + 8]);
    uint4 kta = *reinterpret_cast<const uint4*>(&KTbase[(size_t)mi * 1024 + ds]);
    uint4 ktb = *reinterpret_cast<const uint4*>(&KTbase[(size_t)mi * 1024 + ds + 8]);

    for (int mb = 0; mb < 16; mb++) {
        __syncthreads();
        *reinterpret_cast<uint4*>(&Ks[mi * 72 + ds]) = kva;
        *reinterpret_cast<uint4*>(&Ks[mi * 72 + ds + 8]) = kvb;
        *reinterpret_cast<uint4*>(&KsT[mi * 72 + ds]) = kta;
        *reinterpret_cast<uint4*>(&KsT[mi * 72 + ds + 8]) = ktb;
        __syncthreads();

        {
            int mnext = (mb + 1 < 16 ? mb + 1 : 15) * 64;
            kva = *reinterpret_cast<const uint4*>(&Kbase[(size_t)(mnext + mi) * 64 + ds]);
            kvb = *reinterpret_cast<const uint4*>(&Kbase[(size_t)(mnext + mi) * 64 + ds + 8]);
            kta = *reinterpret_cast<const uint4*>(&KTbase[(size_t)mi * 1024 + mnext + ds]);
            ktb = *reinterpret_cast<const uint4*>(&KTbase[(size_t)mi * 1024 + mnext + ds + 8]);
        }

        f32x4 st[4];
        for (int nt = 0; nt < 4; nt++) {
            bf16x8 bk0 = *reinterpret_cast<bf16x8*>(&Ks[(nt * 16 + ln) * 72 + quad * 8]);
            bf16x8 bk1 = *reinterpret_cast<bf16x8*>(&Ks[(nt * 16 + ln) * 72 + 32 + quad * 8]);
            f32x4 z;
            for (int r = 0; r < 4; r++) z[r] = 0.0f;
            z = MFMA(a0, bk0, z);
            st[nt] = MFMA(a1, bk1, z);
        }

        // softmax numerator: p = exp2(st) (st already includes 1/8 * log2e); no max, no clamp
        for (int r = 0; r < 4; r++) {
            int row = quad * 4 + r;
            float psum = 0.0f;
            for (int nt = 0; nt < 4; nt++) {
                float p = exp2f(st[nt][r]);
                psum += p;
                Pl[wave][row * 72 + nt * 16 + ln] = f2bf_trunc(p);
            }
            lst[r] += psum;
        }

        // PV: O += P(16x64) @ K(64x64)   (Pl wave-private: no barrier)
        bf16x8 pf0 = *reinterpret_cast<bf16x8*>(&Pl[wave][ln * 72 + quad * 8]);
        bf16x8 pf1 = *reinterpret_cast<bf16x8*>(&Pl[wave][ln * 72 + 32 + quad * 8]);
        for (int dt = 0; dt < 4; dt++) {
            bf16x8 bk0 = *reinterpret_cast<bf16x8*>(&KsT[(dt * 16 + ln) * 72 + quad * 8]);
            bf16x8 bk1 = *reinterpret_cast<bf16x8*>(&KsT[(dt * 16 + ln) * 72 + 32 + quad * 8]);
            o[dt] = MFMA(pf0, bk0, o[dt]);
            o[dt] = MFMA(pf1, bk1, o[dt]);
        }
    }

    for (int r = 0; r < 4; r++)
        for (int off = 1; off < 16; off <<= 1) lst[r] += __shfl_xor(lst[r], off, 64);

    u16* out = CTXH + (size_t)bh * 65536;
    for (int r = 0; r < 4; r++) {
        float inv = 1.0f / lst[r];
        int row = lw + quad * 4 + r;
        for (int dt = 0; dt < 4; dt++)
            out[(size_t)row * 64 + dt * 16 + ln] = f2bf(o[dt][r] * inv);
    }
}

// ---------------- layernorm over 768, one block per row; optional second input ----------------
__global__ __launch_bounds__(256) void layernorm_k(const float* __restrict__ in,
                                                   float* __restrict__ outF,
                                                   u16* __restrict__ outB,
                                                   const float* __restrict__ g,
                                                   const float* __restrict__ be,
                                                   const float* __restrict__ in2) {
    __shared__ float red[8];
    int row = blockIdx.x;
    int t = threadIdx.x;
    const float* p = in + (size_t)row * 768;
    float v0 = p[t], v1 = p[t + 256], v2 = p[t + 512];
    if (in2) {
        const float* p2 = in2 + (size_t)row * 768;
        v0 += p2[t]; v1 += p2[t + 256]; v2 += p2[t + 512];
    }
    float s = v0 + v1 + v2;
    float ss = v0 * v0 + v1 * v1 + v2 * v2;
    for (int off = 32; off >= 1; off >>= 1) {
        s += __shfl_xor(s, off, 64);
        ss += __shfl_xor(ss, off, 64);
    }
    int wave = t >> 6, lane = t & 63;
    if (lane == 0) { red[wave] = s; red[4 + wave] = ss; }
    __syncthreads();
    float S = red[0] + red[1] + red[2] + red[3];
    float SS = red[4] + red[5] + red[6] + red[7];
    float mean = S * (1.0f / 768.0f);
    float var = SS * (1.0f / 768.0f) - mean * mean;
    float rstd = rsqrtf(var + 1e-5f);
    float o0 = (v0 - mean) * rstd * g[t] + be[t];
    float o1 = (v1 - mean) * rstd * g[t + 256] + be[t + 256];
    float o2 = (v2 - mean) * rstd * g[t + 512] + be[t + 512];
    float* q = outF + (size_t)row * 768;
    q[t] = o0; q[t + 256] = o1; q[t + 512] = o2;
    if (outB) {
        u16* qb = outB + (size_t)row * 768;
        qb[t] = f2bf(o0); qb[t + 256] = f2bf(o1); qb[t + 512] = f2bf(o2);
    }
}

extern "C" void kernel_launch(void* const* d_in, const int* in_sizes, int n_in,
                              void* d_out, int out_size, void* d_ws, size_t ws_size,
                              hipStream_t stream) {
    const float* x   = (const float*)d_in[0];
    const float* Wq  = (const float*)d_in[1];
    const float* Wk  = (const float*)d_in[2];
    // d_in[3] = Wv — dead code in the reference, skipped.
    const float* Wo  = (const float*)d_in[4];
    const float* W1  = (const float*)d_in[5];
    const float* b1  = (const float*)d_in[6];
    const float* W2  = (const float*)d_in[7];
    const float* b2  = (const float*)d_in[8];
    const float* g1  = (const float*)d_in[9];
    const float* be1 = (const float*)d_in[10];
    const float* g2  = (const float*)d_in[11];
    const float* be2 = (const float*)d_in[12];
    float* out = (float*)d_out;

    const int S = 8192, H = 768, MLP4 = 3072, H2 = 1536;

    char* ws = (char*)d_ws;
    u16* XB   = (u16*)ws;  ws += (size_t)S * H * 2;      // reused as CTXH
    u16* WQKT = (u16*)ws;  ws += (size_t)H2 * H * 2;
    u16* WOT  = (u16*)ws;  ws += (size_t)H * H * 2;      // k-permuted
    u16* W1T  = (u16*)ws;  ws += (size_t)H * MLP4 * 2;
    u16* W2T  = (u16*)ws;  ws += (size_t)H * MLP4 * 2;
    u16* QKB  = (u16*)ws;  ws += (size_t)S * H2 * 2;     // Q (log2-prescaled) | K, row-major
    u16* KH   = (u16*)ws;  ws += (size_t)S * H * 2;      // K head-major
    float* Y  = (float*)ws; ws += (size_t)S * H * 4;
    u16* HB   = (u16*)ws;  ws += (size_t)S * MLP4 * 2;

    u16* CTXH = XB;          // after QK gemm, XB is dead
    u16* X1B  = QKB;         // Q half, dead after attention
    u16* KHT  = HB;          // HB dead until W1 gemm; holds K transposed (12.6 MB < 50 MB)

    // 1. fused prep: x cast + all weight transposes
    prep_k<<<4608, 256, 0, stream>>>(x, Wq, Wk, Wo, W1, W2, XB, WQKT, WOT, W1T, W2T);

    // 2. [Q|K] = X [Wq|Wk]  — 512-thread 8-wave variant (occupancy bracket: 16 waves/CU)
    gemm_bt_k<4, 128, false, 0, false, 512><<<12 * 64, 512, 0, stream>>>(XB, WQKT, S, H2, H, 12, nullptr, QKB, nullptr, nullptr);

    // 3. attention (K repacked head-major + transposed; ctx stays head-major in CTXH)
    head_pack_k<<<dim3(64, 8), 256, 0, stream>>>(QKB + H, H2, KH, KHT);
    attention_k<<<dim3(16, 96), 256, 0, stream>>>(QKB, H2, KH, KHT, CTXH);

    // 4. y = x + ctx Wo ; x1 = LN1(y) in-place + bf16 copy  (round-3 verified config)
    gemm_bt_k<1, 64, true><<<6 * 128, 256, 0, stream>>>(CTXH, WOT, S, H, H, 6, Y, nullptr, x, nullptr);
    layernorm_k<<<S, 256, 0, stream>>>(Y, Y, X1B, g1, be1, nullptr);

    // 5. h = gelu(x1 W1 + b1) ; y2 = x1 + h W2 + b2 ; out = LN2(y2)
    //    W1: 512-thread 8-wave variant. W2: round-3 verified config (TM=64, NS=4, unsplit).
    gemm_bt_k<2, 128, false, 0, false, 512><<<24 * 64, 512, 0, stream>>>(X1B, W1T, S, MLP4, H, 24, nullptr, HB, nullptr, b1);
    gemm_bt_k<3, 64><<<6 * 128, 256, 0, stream>>>(HB, W2T, S, H, MLP4, 6, Y, nullptr, Y, b2);
    layernorm_k<<<S, 256, 0, stream>>>(Y, out, nullptr, g2, be2, nullptr);
}

// Round 15
// 388.587 us; speedup vs baseline: 1.0784x; 1.0187x over previous
//
#include <hip/hip_runtime.h>
#include <math.h>

typedef unsigned short u16;
typedef unsigned int u32;
typedef short bf16x8 __attribute__((ext_vector_type(8)));
typedef float f32x4 __attribute__((ext_vector_type(4)));

#define MFMA(a, b, c) __builtin_amdgcn_mfma_f32_16x16x32_bf16((a), (b), (c), 0, 0, 0)

// async global->LDS, 16B per lane; LDS dest = wave-uniform base + lane*16
#define GLOAD_LDS16(g, l)                                                              \
    __builtin_amdgcn_global_load_lds((const __attribute__((address_space(1))) void*)(g), \
                                     (__attribute__((address_space(3))) void*)(l), 16, 0, 0)

__device__ __forceinline__ u16 f2bf(float f) {
    u32 u = __float_as_uint(f);
    u32 r = (u + 0x7fffu + ((u >> 16) & 1u)) >> 16;
    return (u16)r;
}

__device__ __forceinline__ u16 f2bf_trunc(float f) {  // truncating bf16 (1 VALU op)
    return (u16)(__float_as_uint(f) >> 16);
}

// tanh-form GELU via native exp/rcp
__device__ __forceinline__ float fast_gelu(float z) {
    float u = fminf(1.5957691216f * z * (1.0f + 0.044715f * z * z), 80.0f);
    float e = __expf(u);
    float r = __builtin_amdgcn_rcpf(e + 1.0f);
    return z * e * r;
}

// ================= fused prep: x cast + all weight transposes, one dispatch =================
__device__ void dev_xcast(const float* __restrict__ in, u16* __restrict__ out, int blk) {
    size_t i = ((size_t)blk * 256 + threadIdx.x) * 8;
    const float4* p = reinterpret_cast<const float4*>(in + i);
    float4 a = p[0], b = p[1];
    union { u16 u[8]; uint4 v; } o;
    o.u[0] = f2bf(a.x); o.u[1] = f2bf(a.y); o.u[2] = f2bf(a.z); o.u[3] = f2bf(a.w);
    o.u[4] = f2bf(b.x); o.u[5] = f2bf(b.y); o.u[6] = f2bf(b.z); o.u[7] = f2bf(b.w);
    *reinterpret_cast<uint4*>(out + i) = o.v;
}

__device__ void dev_transpose(const float* __restrict__ in, u16* __restrict__ out,
                              int K, int N, int bx, int by, float* tile /* [64][65] */) {
    int k0 = by * 64, n0 = bx * 64;
    int t = threadIdx.x;
    for (int p = 0; p < 16; p++) {
        int idx = t + p * 256;
        int r = idx >> 6, c = idx & 63;
        tile[r * 65 + c] = in[(size_t)(k0 + r) * N + n0 + c];
    }
    __syncthreads();
    for (int p = 0; p < 16; p++) {
        int idx = t + p * 256;
        int nr = idx >> 6, nc = idx & 63;
        out[(size_t)(n0 + nr) * K + k0 + nc] = f2bf(tile[nc * 65 + nr]);
    }
}

// Wo transpose with k-permute: out[col][n*64+d] = Wo[d*12+n][col]
__device__ void dev_wo(const float* __restrict__ in, u16* __restrict__ out,
                       int bx, int by, float* tile /* [96][65] */) {
    int k0 = by * 96, n0 = bx * 64;
    int t = threadIdx.x;
    for (int p = 0; p < 24; p++) {
        int idx = t + p * 256;
        int r = idx >> 6, c = idx & 63;
        tile[r * 65 + c] = in[(size_t)(k0 + r) * 768 + n0 + c];
    }
    __syncthreads();
    for (int p = 0; p < 3; p++) {
        int idx = t + p * 256;  // (col c)*12 + n
        int c = idx / 12, n = idx % 12;
        union { u16 u[8]; uint4 v; } o;
        for (int j = 0; j < 8; j++) o.u[j] = f2bf(tile[(j * 12 + n) * 65 + c]);
        *reinterpret_cast<uint4*>(&out[(size_t)(n0 + c) * 768 + n * 64 + by * 8]) = o.v;
    }
}

__global__ __launch_bounds__(256) void prep_k(const float* __restrict__ x,
                                              const float* __restrict__ Wq,
                                              const float* __restrict__ Wk,
                                              const float* __restrict__ Wo,
                                              const float* __restrict__ W1,
                                              const float* __restrict__ W2,
                                              u16* __restrict__ XB,
                                              u16* __restrict__ WQKT,
                                              u16* __restrict__ WOT,
                                              u16* __restrict__ W1T,
                                              u16* __restrict__ W2T) {
    __shared__ float tile[96 * 65];
    int bid = blockIdx.x;
    if (bid < 3072) {
        dev_xcast(x, XB, bid);
    } else if (bid < 3216) {
        int b = bid - 3072; dev_transpose(Wq, WQKT, 768, 768, b % 12, b / 12, tile);
    } else if (bid < 3360) {
        int b = bid - 3216; dev_transpose(Wk, WQKT + (size_t)768 * 768, 768, 768, b % 12, b / 12, tile);
    } else if (bid < 3456) {
        int b = bid - 3360; dev_wo(Wo, WOT, b % 12, b / 12, tile);
    } else if (bid < 4032) {
        int b = bid - 3456; dev_transpose(W1, W1T, 768, 3072, b % 48, b / 48, tile);
    } else {
        int b = bid - 4032; dev_transpose(W2, W2T, 3072, 768, b % 12, b / 12, tile);
    }
}

// ---------------- head pack: in (S x ld, col base pre-offset) -> KH (96 x 1024 x 64) ----------------
// Also emits KHT (96 x 64 x 1024): KHT[head][d][m] = K[b][m][d*12+n].
__global__ __launch_bounds__(256) void head_pack_k(const u16* __restrict__ in, int ld,
                                                   u16* __restrict__ out,
                                                   u16* __restrict__ outT) {
    __shared__ u16 tile[16 * 768];
    int b = blockIdx.y;
    int l0 = blockIdx.x * 16;
    int t = threadIdx.x;
    for (int p = 0; p < 6; p++) {
        int c = t + p * 256;
        int li = c / 96, dc = c % 96;
        *reinterpret_cast<uint4*>(&tile[li * 768 + dc * 8]) =
            *reinterpret_cast<const uint4*>(&in[(size_t)(b * 1024 + l0 + li) * ld + dc * 8]);
    }
    __syncthreads();
    for (int p = 0; p < 6; p++) {
        int c = t + p * 256;
        int n = c >> 7, rem = c & 127, li = rem >> 3, k8 = rem & 7;
        union { u16 u[8]; uint4 v; } o;
        for (int j = 0; j < 8; j++) o.u[j] = tile[li * 768 + (k8 * 8 + j) * 12 + n];
        *reinterpret_cast<uint4*>(&out[(size_t)((b * 12 + n) * 1024 + l0 + li) * 64 + k8 * 8]) = o.v;
    }
    // transposed copy: 6 passes x 256 threads cover 12 heads x 64 d x 2 halves (8 m each)
    for (int p = 0; p < 6; p++) {
        int c = t + p * 256;                 // 0..1535
        int n = c >> 7;                      // head 0..11
        int rem = c & 127;
        int d = rem >> 1;                    // 0..63
        int half = rem & 1;                  // m-offset 0 or 8
        union { u16 u[8]; uint4 v; } o;
        for (int j = 0; j < 8; j++) o.u[j] = tile[(half * 8 + j) * 768 + d * 12 + n];
        *reinterpret_cast<uint4*>(
            &outT[((size_t)(b * 12 + n) * 64 + d) * 1024 + l0 + half * 8]) = o.v;
    }
}

// ---------------- GEMM: C(MxN) = A(MxK bf16) @ BT(NxK bf16)^T ----------------
// TM x 128 tile, NS-stage pipeline, ONE raw s_barrier per K-step, counted per-wave vmcnt.
// NT=256: 4 waves.  NT=512 + TM=128: 8 waves, 64x32 subtiles (r9 bracket fix).
// NT=512 + TM=64 (ATHIN, W2 shape): 8 waves, 32x32 subtiles, acc=16 AGPR -> target
//   <=64-reg bracket (8 waves/SIMD, m69) -> 24 waves/CU vs 12. A tile (4 KB) staged by
//   waves 0-3 only (wave-uniform guard); per-wave counted vmcnt: A-waves 4, B-only 2.
// AH: A is CTXH [b*12+n][l][64], logical k = n*64+d (TM=64; BT rows permuted).
// EPI 1: outF = resid + acc;  2: outB = bf16(gelu(acc + bias[col]));
// EPI 3: outF = resid + acc + bias[col];
// EPI 4: outB = bf16(acc * (col<768 ? 0.125*log2e : 1))  [QK proj; Q in log2-domain]
template <int EPI, int TM, bool AH = false, int NSO = 0, bool KSPLIT = false, int NT = 256>
__global__ __launch_bounds__(NT) void gemm_bt_k(const u16* __restrict__ A,
                                                const u16* __restrict__ BT,
                                                int M, int N, int K, int NBX,
                                                float* __restrict__ outF,
                                                u16* __restrict__ outB,
                                                const float* __restrict__ resid,
                                                const float* __restrict__ bias) {
    constexpr int NS = NSO ? NSO : ((TM == 64) ? 4 : 3);
    constexpr int WN = (NT == 512) ? 4 : 2;          // waves along N
    constexpr int MI = (TM / 2) / 16;                // A-frag repeats per wave
    constexpr int NJ = (128 / WN) / 16;              // B-frag repeats per wave
    constexpr bool ATHIN = (TM == 64 && NT == 512);  // A tile smaller than thread count
    constexpr int ALD = (TM == 128 && NT == 256) ? 2 : 1;  // A loads / thread / step
    constexpr int BLD = (NT == 256) ? 2 : 1;               // B loads / thread / step
    constexpr int LPS = ALD + BLD;
    constexpr int VC = LPS * (NS - 2);               // counted vmcnt at the wait point
    __shared__ __align__(16) u16 As[NS][TM * 32];
    __shared__ __align__(16) u16 Bs[NS][128 * 32];

    int L = blockIdx.x;
    int kp = 0;
    if constexpr (KSPLIT) {
        int half = gridDim.x >> 1;
        if (L >= half) { kp = 1; L -= half; }
    }
    int bx = (L >> 3) % NBX;
    int by = (L / (8 * NBX)) * 8 + (L & 7);
    int m0 = by * TM, n0 = bx * 128;

    int t = threadIdx.x;
    int wave = t >> 6, lane = t & 63;
    int wr = (wave / WN) * (TM / 2), wc = (wave % WN) * (128 / WN);
    int ln = lane & 15, quad = lane >> 4;
    int sw = quad ^ ((ln >> 1) & 3);

    int e0 = t, e1 = t + 256;                        // e1 only used when NT==256
    int r0 = e0 >> 2, c0 = (e0 & 3) ^ ((r0 >> 1) & 3);
    int r1 = e1 >> 2, c1 = (e1 & 3) ^ ((r1 >> 1) & 3);
    int kofs = 0;
    if constexpr (KSPLIT) kofs = kp * (K >> 1);
    int ahk = 0;
    if constexpr (KSPLIT && AH) ahk = kp * (K >> 4);
    const u16* A0 = A + (size_t)(m0 + (ATHIN ? (r0 & 63) : r0)) * K + kofs + c0 * 8;
    const u16* A1 = A + (size_t)(m0 + r1) * K + kofs + c1 * 8;  // ALD==2 only
    const u16* B0 = BT + (size_t)(n0 + r0) * K + kofs + c0 * 8;
    const u16* B1 = BT + (size_t)(n0 + r1) * K + kofs + c1 * 8; // BLD==2 only
    const u16* Abase = nullptr;
    if constexpr (AH) {
        int m = m0 + r0;
        Abase = A + ((size_t)(m >> 10) * 12288 + (m & 1023)) * 64;
    }

    int nk = K >> 5;
    if constexpr (KSPLIT) nk >>= 1;

    f32x4 acc[MI][NJ];
    for (int i = 0; i < MI; i++)
        for (int j = 0; j < NJ; j++)
            for (int r = 0; r < 4; r++) acc[i][j][r] = 0.0f;

    for (int s = 0; s < NS - 1; s++) {
        if constexpr (AH) {
            int col8 = ahk + s * 4 + c0;
            GLOAD_LDS16(Abase + (col8 >> 3) * 65536 + (col8 & 7) * 8, &As[s][e0 * 8]);
        } else if constexpr (ATHIN) {
            if (wave < 4) GLOAD_LDS16(A0 + s * 32, &As[s][e0 * 8]);  // wave-uniform guard
        } else {
            GLOAD_LDS16(A0 + s * 32, &As[s][e0 * 8]);
            if constexpr (ALD == 2) GLOAD_LDS16(A1 + s * 32, &As[s][e1 * 8]);
        }
        GLOAD_LDS16(B0 + s * 32, &Bs[s][e0 * 8]);
        if constexpr (BLD == 2) GLOAD_LDS16(B1 + s * 32, &Bs[s][e1 * 8]);
    }

    for (int kb = 0; kb < nk; kb += NS) {
#pragma unroll
        for (int s = 0; s < NS; s++) {
            int k = kb + s;
            if constexpr (ATHIN) {
                // per-wave counted vmcnt: waves 0-3 issue 2 loads/step, waves 4-7 issue 1
                if (wave < 4) asm volatile("s_waitcnt vmcnt(4)" ::: "memory");
                else          asm volatile("s_waitcnt vmcnt(2)" ::: "memory");
            }
            else if constexpr (VC == 6) asm volatile("s_waitcnt vmcnt(6)" ::: "memory");
            else if constexpr (VC == 4) asm volatile("s_waitcnt vmcnt(4)" ::: "memory");
            else if constexpr (VC == 3) asm volatile("s_waitcnt vmcnt(3)" ::: "memory");
            else if constexpr (VC == 2) asm volatile("s_waitcnt vmcnt(2)" ::: "memory");
            else                        asm volatile("s_waitcnt vmcnt(0)" ::: "memory");
            asm volatile("s_barrier" ::: "memory");
            {
                int ks = k + NS - 1 < nk ? k + NS - 1 : nk - 1;  // clamped: uniform in-flight count
                int stage = (s + NS - 1) % NS;  // s constant under unroll -> folds
                if constexpr (AH) {
                    int col8 = ahk + ks * 4 + c0;
                    GLOAD_LDS16(Abase + (col8 >> 3) * 65536 + (col8 & 7) * 8, &As[stage][e0 * 8]);
                } else if constexpr (ATHIN) {
                    if (wave < 4) GLOAD_LDS16(A0 + ks * 32, &As[stage][e0 * 8]);
                } else {
                    GLOAD_LDS16(A0 + ks * 32, &As[stage][e0 * 8]);
                    if constexpr (ALD == 2) GLOAD_LDS16(A1 + ks * 32, &As[stage][e1 * 8]);
                }
                GLOAD_LDS16(B0 + ks * 32, &Bs[stage][e0 * 8]);
                if constexpr (BLD == 2) GLOAD_LDS16(B1 + ks * 32, &Bs[stage][e1 * 8]);
            }
            const u16* as = As[s];
            const u16* bs = Bs[s];
            bf16x8 afr[MI], bfr[NJ];
            for (int i = 0; i < MI; i++)
                afr[i] = *reinterpret_cast<const bf16x8*>(&as[(wr + i * 16 + ln) * 32 + sw * 8]);
            for (int j = 0; j < NJ; j++)
                bfr[j] = *reinterpret_cast<const bf16x8*>(&bs[(wc + j * 16 + ln) * 32 + sw * 8]);
            for (int i = 0; i < MI; i++)
                for (int j = 0; j < NJ; j++)
                    acc[i][j] = MFMA(afr[i], bfr[j], acc[i][j]);
        }
    }

    for (int i = 0; i < MI; i++) {
        for (int j = 0; j < NJ; j++) {
            int col = n0 + wc + j * 16 + ln;
            for (int r = 0; r < 4; r++) {
                int row = m0 + wr + i * 16 + quad * 4 + r;
                size_t idx = (size_t)row * N + col;
                float v = acc[i][j][r];
                if constexpr (EPI == 1) {
                    if constexpr (KSPLIT) {
                        if (kp == 0) outF[idx] = resid[idx] + v;
                        else reinterpret_cast<float*>(outB)[idx] = v;
                    } else {
                        outF[idx] = resid[idx] + v;
                    }
                } else if constexpr (EPI == 2) {
                    outB[idx] = f2bf(fast_gelu(v + bias[col]));
                } else if constexpr (EPI == 3) {
                    if constexpr (KSPLIT) {
                        if (kp == 0) outF[idx] = resid[idx] + v + bias[col];
                        else reinterpret_cast<float*>(outB)[idx] = v;
                    } else {
                        outF[idx] = resid[idx] + v + bias[col];
                    }
                } else {
                    // 0.125 * log2(e): Q scores land in log2 domain for exp2 softmax
                    outB[idx] = f2bf(col < 768 ? v * 0.18033688011112042f : v);
                }
            }
        }
    }
}

// ---------------- flash-style attention (ctx = softmax @ K), Q prescaled to log2 domain ----------------
__global__ __launch_bounds__(256) void attention_k(const u16* __restrict__ QB, int ldq,
                                                   const u16* __restrict__ KH,
                                                   const u16* __restrict__ KHT,
                                                   u16* __restrict__ CTXH) {
    __shared__ __align__(16) u16 Ks[64 * 72];   // [m'][d]
    __shared__ __align__(16) u16 KsT[64 * 72];  // [d][m']
    __shared__ __align__(16) u16 Pl[4][16 * 72];
    int bh = blockIdx.y;
    int b = bh / 12, n = bh % 12;
    int l0 = blockIdx.x * 64;
    int t = threadIdx.x, wave = t >> 6, lane = t & 63;
    int ln = lane & 15, quad = lane >> 4;
    int lw = l0 + wave * 16;

    // Q A-fragments (strided gather, once per block); Q already scaled by 0.125*log2e
    bf16x8 a0, a1;
    {
        union { u16 u[8]; bf16x8 v; } q0, q1;
        const u16* qrow = QB + (size_t)(b * 1024 + lw + ln) * ldq + n;
        for (int j = 0; j < 8; j++) {
            q0.u[j] = qrow[(quad * 8 + j) * 12];
            q1.u[j] = qrow[(32 + quad * 8 + j) * 12];
        }
        a0 = q0.v; a1 = q1.v;
    }

    f32x4 o[4];
    for (int dt = 0; dt < 4; dt++)
        for (int r = 0; r < 4; r++) o[dt][r] = 0.0f;
    float lst[4];
    for (int r = 0; r < 4; r++) lst[r] = 0.0f;

    const u16* Kbase  = KH  + (size_t)bh * 65536;
    const u16* KTbase = KHT + (size_t)bh * 65536;  // [d][m], 64 rows x 1024
    int mi = t & 63, ds = (t >> 6) * 16;

    uint4 kva = *reinterpret_cast<const uint4*>(&Kbase[(size_t)mi * 64 + ds]);
    uint4 kvb = *reinterpret_cast<const uint4*>(&Kbase[(size_t)mi * 64 + ds + 8]);
    uint4 kta = *reinterpret_cast<const uint4*>(&KTbase[(size_t)mi * 1024 + ds]);
    uint4 ktb = *reinterpret_cast<const uint4*>(&KTbase[(size_t)mi * 1024 + ds + 8]);

    for (int mb = 0; mb < 16; mb++) {
        __syncthreads();
        *reinterpret_cast<uint4*>(&Ks[mi * 72 + ds]) = kva;
        *reinterpret_cast<uint4*>(&Ks[mi * 72 + ds + 8]) = kvb;
        *reinterpret_cast<uint4*>(&KsT[mi * 72 + ds]) = kta;
        *reinterpret_cast<uint4*>(&KsT[mi * 72 + ds + 8]) = ktb;
        __syncthreads();

        {
            int mnext = (mb + 1 < 16 ? mb + 1 : 15) * 64;
            kva = *reinterpret_cast<const uint4*>(&Kbase[(size_t)(mnext + mi) * 64 + ds]);
            kvb = *reinterpret_cast<const uint4*>(&Kbase[(size_t)(mnext + mi) * 64 + ds + 8]);
            kta = *reinterpret_cast<const uint4*>(&KTbase[(size_t)mi * 1024 + mnext + ds]);
            ktb = *reinterpret_cast<const uint4*>(&KTbase[(size_t)mi * 1024 + mnext + ds + 8]);
        }

        f32x4 st[4];
        for (int nt = 0; nt < 4; nt++) {
            bf16x8 bk0 = *reinterpret_cast<bf16x8*>(&Ks[(nt * 16 + ln) * 72 + quad * 8]);
            bf16x8 bk1 = *reinterpret_cast<bf16x8*>(&Ks[(nt * 16 + ln) * 72 + 32 + quad * 8]);
            f32x4 z;
            for (int r = 0; r < 4; r++) z[r] = 0.0f;
            z = MFMA(a0, bk0, z);
            st[nt] = MFMA(a1, bk1, z);
        }

        // softmax numerator: p = exp2(st) (st already includes 1/8 * log2e); no max, no clamp
        for (int r = 0; r < 4; r++) {
            int row = quad * 4 + r;
            float psum = 0.0f;
            for (int nt = 0; nt < 4; nt++) {
                float p = exp2f(st[nt][r]);
                psum += p;
                Pl[wave][row * 72 + nt * 16 + ln] = f2bf_trunc(p);
            }
            lst[r] += psum;
        }

        // PV: O += P(16x64) @ K(64x64)   (Pl wave-private: no barrier)
        bf16x8 pf0 = *reinterpret_cast<bf16x8*>(&Pl[wave][ln * 72 + quad * 8]);
        bf16x8 pf1 = *reinterpret_cast<bf16x8*>(&Pl[wave][ln * 72 + 32 + quad * 8]);
        for (int dt = 0; dt < 4; dt++) {
            bf16x8 bk0 = *reinterpret_cast<bf16x8*>(&KsT[(dt * 16 + ln) * 72 + quad * 8]);
            bf16x8 bk1 = *reinterpret_cast<bf16x8*>(&KsT[(dt * 16 + ln) * 72 + 32 + quad * 8]);
            o[dt] = MFMA(pf0, bk0, o[dt]);
            o[dt] = MFMA(pf1, bk1, o[dt]);
        }
    }

    for (int r = 0; r < 4; r++)
        for (int off = 1; off < 16; off <<= 1) lst[r] += __shfl_xor(lst[r], off, 64);

    u16* out = CTXH + (size_t)bh * 65536;
    for (int r = 0; r < 4; r++) {
        float inv = 1.0f / lst[r];
        int row = lw + quad * 4 + r;
        for (int dt = 0; dt < 4; dt++)
            out[(size_t)row * 64 + dt * 16 + ln] = f2bf(o[dt][r] * inv);
    }
}

// ---------------- layernorm over 768, one block per row; optional second input ----------------
__global__ __launch_bounds__(256) void layernorm_k(const float* __restrict__ in,
                                                   float* __restrict__ outF,
                                                   u16* __restrict__ outB,
                                                   const float* __restrict__ g,
                                                   const float* __restrict__ be,
                                                   const float* __restrict__ in2) {
    __shared__ float red[8];
    int row = blockIdx.x;
    int t = threadIdx.x;
    const float* p = in + (size_t)row * 768;
    float v0 = p[t], v1 = p[t + 256], v2 = p[t + 512];
    if (in2) {
        const float* p2 = in2 + (size_t)row * 768;
        v0 += p2[t]; v1 += p2[t + 256]; v2 += p2[t + 512];
    }
    float s = v0 + v1 + v2;
    float ss = v0 * v0 + v1 * v1 + v2 * v2;
    for (int off = 32; off >= 1; off >>= 1) {
        s += __shfl_xor(s, off, 64);
        ss += __shfl_xor(ss, off, 64);
    }
    int wave = t >> 6, lane = t & 63;
    if (lane == 0) { red[wave] = s; red[4 + wave] = ss; }
    __syncthreads();
    float S = red[0] + red[1] + red[2] + red[3];
    float SS = red[4] + red[5] + red[6] + red[7];
    float mean = S * (1.0f / 768.0f);
    float var = SS * (1.0f / 768.0f) - mean * mean;
    float rstd = rsqrtf(var + 1e-5f);
    float o0 = (v0 - mean) * rstd * g[t] + be[t];
    float o1 = (v1 - mean) * rstd * g[t + 256] + be[t + 256];
    float o2 = (v2 - mean) * rstd * g[t + 512] + be[t + 512];
    float* q = outF + (size_t)row * 768;
    q[t] = o0; q[t + 256] = o1; q[t + 512] = o2;
    if (outB) {
        u16* qb = outB + (size_t)row * 768;
        qb[t] = f2bf(o0); qb[t + 256] = f2bf(o1); qb[t + 512] = f2bf(o2);
    }
}

extern "C" void kernel_launch(void* const* d_in, const int* in_sizes, int n_in,
                              void* d_out, int out_size, void* d_ws, size_t ws_size,
                              hipStream_t stream) {
    const float* x   = (const float*)d_in[0];
    const float* Wq  = (const float*)d_in[1];
    const float* Wk  = (const float*)d_in[2];
    // d_in[3] = Wv — dead code in the reference, skipped.
    const float* Wo  = (const float*)d_in[4];
    const float* W1  = (const float*)d_in[5];
    const float* b1  = (const float*)d_in[6];
    const float* W2  = (const float*)d_in[7];
    const float* b2  = (const float*)d_in[8];
    const float* g1  = (const float*)d_in[9];
    const float* be1 = (const float*)d_in[10];
    const float* g2  = (const float*)d_in[11];
    const float* be2 = (const float*)d_in[12];
    float* out = (float*)d_out;

    const int S = 8192, H = 768, MLP4 = 3072, H2 = 1536;

    char* ws = (char*)d_ws;
    u16* XB   = (u16*)ws;  ws += (size_t)S * H * 2;      // reused as CTXH
    u16* WQKT = (u16*)ws;  ws += (size_t)H2 * H * 2;
    u16* WOT  = (u16*)ws;  ws += (size_t)H * H * 2;      // k-permuted
    u16* W1T  = (u16*)ws;  ws += (size_t)H * MLP4 * 2;
    u16* W2T  = (u16*)ws;  ws += (size_t)H * MLP4 * 2;
    u16* QKB  = (u16*)ws;  ws += (size_t)S * H2 * 2;     // Q (log2-prescaled) | K, row-major
    u16* KH   = (u16*)ws;  ws += (size_t)S * H * 2;      // K head-major
    float* Y  = (float*)ws; ws += (size_t)S * H * 4;
    u16* HB   = (u16*)ws;  ws += (size_t)S * MLP4 * 2;

    u16* CTXH = XB;          // after QK gemm, XB is dead
    u16* X1B  = QKB;         // Q half, dead after attention
    u16* KHT  = HB;          // HB dead until W1 gemm; holds K transposed (12.6 MB < 50 MB)

    // 1. fused prep: x cast + all weight transposes
    prep_k<<<4608, 256, 0, stream>>>(x, Wq, Wk, Wo, W1, W2, XB, WQKT, WOT, W1T, W2T);

    // 2. [Q|K] = X [Wq|Wk]  — 512-thread 8-wave variant
    gemm_bt_k<4, 128, false, 0, false, 512><<<12 * 64, 512, 0, stream>>>(XB, WQKT, S, H2, H, 12, nullptr, QKB, nullptr, nullptr);

    // 3. attention (K repacked head-major + transposed; ctx stays head-major in CTXH)
    head_pack_k<<<dim3(64, 8), 256, 0, stream>>>(QKB + H, H2, KH, KHT);
    attention_k<<<dim3(16, 96), 256, 0, stream>>>(QKB, H2, KH, KHT, CTXH);

    // 4. y = x + ctx Wo ; x1 = LN1(y) in-place + bf16 copy  (round-3 verified config)
    gemm_bt_k<1, 64, true><<<6 * 128, 256, 0, stream>>>(CTXH, WOT, S, H, H, 6, Y, nullptr, x, nullptr);
    layernorm_k<<<S, 256, 0, stream>>>(Y, Y, X1B, g1, be1, nullptr);

    // 5. h = gelu(x1 W1 + b1) ; y2 = x1 + h W2 + b2 ; out = LN2(y2)
    //    W1: 512-thread 8-wave. W2: 512-thread ATHIN variant (acc 16 AGPR ->
    //    <=64-reg bracket -> 24 waves/CU target; same NS=4/BK=32 verified pipeline).
    gemm_bt_k<2, 128, false, 0, false, 512><<<24 * 64, 512, 0, stream>>>(X1B, W1T, S, MLP4, H, 24, nullptr, HB, nullptr, b1);
    gemm_bt_k<3, 64, false, 0, false, 512><<<6 * 128, 512, 0, stream>>>(HB, W2T, S, H, MLP4, 6, Y, nullptr, Y, b2);
    layernorm_k<<<S, 256, 0, stream>>>(Y, out, nullptr, g2, be2, nullptr);
}

// Round 19
// 373.802 us; speedup vs baseline: 1.1210x; 1.0396x over previous
//
#include <hip/hip_runtime.h>
#include <math.h>

typedef unsigned short u16;
typedef unsigned int u32;
typedef short bf16x8 __attribute__((ext_vector_type(8)));
typedef float f32x4 __attribute__((ext_vector_type(4)));

#define MFMA(a, b, c) __builtin_amdgcn_mfma_f32_16x16x32_bf16((a), (b), (c), 0, 0, 0)

// async global->LDS, 16B per lane; LDS dest = wave-uniform base + lane*16
#define GLOAD_LDS16(g, l)                                                              \
    __builtin_amdgcn_global_load_lds((const __attribute__((address_space(1))) void*)(g), \
                                     (__attribute__((address_space(3))) void*)(l), 16, 0, 0)

__device__ __forceinline__ u16 f2bf(float f) {
    u32 u = __float_as_uint(f);
    u32 r = (u + 0x7fffu + ((u >> 16) & 1u)) >> 16;
    return (u16)r;
}

__device__ __forceinline__ u16 f2bf_trunc(float f) {  // truncating bf16 (1 VALU op)
    return (u16)(__float_as_uint(f) >> 16);
}

// tanh-form GELU via native exp/rcp
__device__ __forceinline__ float fast_gelu(float z) {
    float u = fminf(1.5957691216f * z * (1.0f + 0.044715f * z * z), 80.0f);
    float e = __expf(u);
    float r = __builtin_amdgcn_rcpf(e + 1.0f);
    return z * e * r;
}

// ================= fused prep: x cast + all weight transposes, one dispatch =================
__device__ void dev_xcast(const float* __restrict__ in, u16* __restrict__ out, int blk) {
    size_t i = ((size_t)blk * 256 + threadIdx.x) * 8;
    const float4* p = reinterpret_cast<const float4*>(in + i);
    float4 a = p[0], b = p[1];
    union { u16 u[8]; uint4 v; } o;
    o.u[0] = f2bf(a.x); o.u[1] = f2bf(a.y); o.u[2] = f2bf(a.z); o.u[3] = f2bf(a.w);
    o.u[4] = f2bf(b.x); o.u[5] = f2bf(b.y); o.u[6] = f2bf(b.z); o.u[7] = f2bf(b.w);
    *reinterpret_cast<uint4*>(out + i) = o.v;
}

__device__ void dev_transpose(const float* __restrict__ in, u16* __restrict__ out,
                              int K, int N, int bx, int by, float* tile /* [64][65] */) {
    int k0 = by * 64, n0 = bx * 64;
    int t = threadIdx.x;
    for (int p = 0; p < 16; p++) {
        int idx = t + p * 256;
        int r = idx >> 6, c = idx & 63;
        tile[r * 65 + c] = in[(size_t)(k0 + r) * N + n0 + c];
    }
    __syncthreads();
    for (int p = 0; p < 16; p++) {
        int idx = t + p * 256;
        int nr = idx >> 6, nc = idx & 63;
        out[(size_t)(n0 + nr) * K + k0 + nc] = f2bf(tile[nc * 65 + nr]);
    }
}

// Wo transpose with k-permute: out[col][n*64+d] = Wo[d*12+n][col]
__device__ void dev_wo(const float* __restrict__ in, u16* __restrict__ out,
                       int bx, int by, float* tile /* [96][65] */) {
    int k0 = by * 96, n0 = bx * 64;
    int t = threadIdx.x;
    for (int p = 0; p < 24; p++) {
        int idx = t + p * 256;
        int r = idx >> 6, c = idx & 63;
        tile[r * 65 + c] = in[(size_t)(k0 + r) * 768 + n0 + c];
    }
    __syncthreads();
    for (int p = 0; p < 3; p++) {
        int idx = t + p * 256;  // (col c)*12 + n
        int c = idx / 12, n = idx % 12;
        union { u16 u[8]; uint4 v; } o;
        for (int j = 0; j < 8; j++) o.u[j] = f2bf(tile[(j * 12 + n) * 65 + c]);
        *reinterpret_cast<uint4*>(&out[(size_t)(n0 + c) * 768 + n * 64 + by * 8]) = o.v;
    }
}

__global__ __launch_bounds__(256) void prep_k(const float* __restrict__ x,
                                              const float* __restrict__ Wq,
                                              const float* __restrict__ Wk,
                                              const float* __restrict__ Wo,
                                              const float* __restrict__ W1,
                                              const float* __restrict__ W2,
                                              u16* __restrict__ XB,
                                              u16* __restrict__ WQKT,
                                              u16* __restrict__ WOT,
                                              u16* __restrict__ W1T,
                                              u16* __restrict__ W2T) {
    __shared__ float tile[96 * 65];
    int bid = blockIdx.x;
    if (bid < 3072) {
        dev_xcast(x, XB, bid);
    } else if (bid < 3216) {
        int b = bid - 3072; dev_transpose(Wq, WQKT, 768, 768, b % 12, b / 12, tile);
    } else if (bid < 3360) {
        int b = bid - 3216; dev_transpose(Wk, WQKT + (size_t)768 * 768, 768, 768, b % 12, b / 12, tile);
    } else if (bid < 3456) {
        int b = bid - 3360; dev_wo(Wo, WOT, b % 12, b / 12, tile);
    } else if (bid < 4032) {
        int b = bid - 3456; dev_transpose(W1, W1T, 768, 3072, b % 48, b / 48, tile);
    } else {
        int b = bid - 4032; dev_transpose(W2, W2T, 3072, 768, b % 12, b / 12, tile);
    }
}

// ---------------- head pack: in (S x ld, col base pre-offset) -> KH (96 x 1024 x 64) ----------------
// Also emits KHT (96 x 64 x 1024): KHT[head][d][m] = K[b][m][d*12+n].
__global__ __launch_bounds__(256) void head_pack_k(const u16* __restrict__ in, int ld,
                                                   u16* __restrict__ out,
                                                   u16* __restrict__ outT) {
    __shared__ u16 tile[16 * 768];
    int b = blockIdx.y;
    int l0 = blockIdx.x * 16;
    int t = threadIdx.x;
    for (int p = 0; p < 6; p++) {
        int c = t + p * 256;
        int li = c / 96, dc = c % 96;
        *reinterpret_cast<uint4*>(&tile[li * 768 + dc * 8]) =
            *reinterpret_cast<const uint4*>(&in[(size_t)(b * 1024 + l0 + li) * ld + dc * 8]);
    }
    __syncthreads();
    for (int p = 0; p < 6; p++) {
        int c = t + p * 256;
        int n = c >> 7, rem = c & 127, li = rem >> 3, k8 = rem & 7;
        union { u16 u[8]; uint4 v; } o;
        for (int j = 0; j < 8; j++) o.u[j] = tile[li * 768 + (k8 * 8 + j) * 12 + n];
        *reinterpret_cast<uint4*>(&out[(size_t)((b * 12 + n) * 1024 + l0 + li) * 64 + k8 * 8]) = o.v;
    }
    // transposed copy: 6 passes x 256 threads cover 12 heads x 64 d x 2 halves (8 m each)
    for (int p = 0; p < 6; p++) {
        int c = t + p * 256;                 // 0..1535
        int n = c >> 7;                      // head 0..11
        int rem = c & 127;
        int d = rem >> 1;                    // 0..63
        int half = rem & 1;                  // m-offset 0 or 8
        union { u16 u[8]; uint4 v; } o;
        for (int j = 0; j < 8; j++) o.u[j] = tile[(half * 8 + j) * 768 + d * 12 + n];
        *reinterpret_cast<uint4*>(
            &outT[((size_t)(b * 12 + n) * 64 + d) * 1024 + l0 + half * 8]) = o.v;
    }
}

// ---------------- GEMM: C(MxN) = A(MxK bf16) @ BT(NxK bf16)^T ----------------
// TM x 128 tile, NS-stage pipeline, ONE raw s_barrier per K-step, counted per-wave vmcnt.
// NT=256: 4 waves.  NT=512 + TM=128: 8 waves, 64x32 subtiles.
// NT=512 + TM=64 (ATHIN): 8 waves, 32x32 subtiles; A staged by waves 0-3 only.
// W2 uses TM=128/NT=512/NSO=4: halves block count (384 blocks, 144 block-steps/CU
// vs 288) — r15 proved per-block-step cost is occupancy-invariant, so fewer step-slots
// is the lever. NSO=4 gives VC=4 (2-step prefetch cover > HBM latency).
// AH: A is CTXH [b*12+n][l][64], logical k = n*64+d (TM=64; BT rows permuted).
// EPI 1: outF = resid + acc;  2: outB = bf16(gelu(acc + bias[col]));
// EPI 3: outF = resid + acc + bias[col];
// EPI 4: outB = bf16(acc * (col<768 ? 0.125*log2e : 1))  [QK proj; Q in log2-domain]
template <int EPI, int TM, bool AH = false, int NSO = 0, bool KSPLIT = false, int NT = 256>
__global__ __launch_bounds__(NT) void gemm_bt_k(const u16* __restrict__ A,
                                                const u16* __restrict__ BT,
                                                int M, int N, int K, int NBX,
                                                float* __restrict__ outF,
                                                u16* __restrict__ outB,
                                                const float* __restrict__ resid,
                                                const float* __restrict__ bias) {
    constexpr int NS = NSO ? NSO : ((TM == 64) ? 4 : 3);
    constexpr int WN = (NT == 512) ? 4 : 2;          // waves along N
    constexpr int MI = (TM / 2) / 16;                // A-frag repeats per wave
    constexpr int NJ = (128 / WN) / 16;              // B-frag repeats per wave
    constexpr bool ATHIN = (TM == 64 && NT == 512);  // A tile smaller than thread count
    constexpr int ALD = (TM == 128 && NT == 256) ? 2 : 1;  // A loads / thread / step
    constexpr int BLD = (NT == 256) ? 2 : 1;               // B loads / thread / step
    constexpr int LPS = ALD + BLD;
    constexpr int VC = LPS * (NS - 2);               // counted vmcnt at the wait point
    __shared__ __align__(16) u16 As[NS][TM * 32];
    __shared__ __align__(16) u16 Bs[NS][128 * 32];

    int L = blockIdx.x;
    int kp = 0;
    if constexpr (KSPLIT) {
        int half = gridDim.x >> 1;
        if (L >= half) { kp = 1; L -= half; }
    }
    int bx = (L >> 3) % NBX;
    int by = (L / (8 * NBX)) * 8 + (L & 7);
    int m0 = by * TM, n0 = bx * 128;

    int t = threadIdx.x;
    int wave = t >> 6, lane = t & 63;
    int wr = (wave / WN) * (TM / 2), wc = (wave % WN) * (128 / WN);
    int ln = lane & 15, quad = lane >> 4;
    int sw = quad ^ ((ln >> 1) & 3);

    int e0 = t, e1 = t + 256;                        // e1 only used when NT==256
    int r0 = e0 >> 2, c0 = (e0 & 3) ^ ((r0 >> 1) & 3);
    int r1 = e1 >> 2, c1 = (e1 & 3) ^ ((r1 >> 1) & 3);
    int kofs = 0;
    if constexpr (KSPLIT) kofs = kp * (K >> 1);
    int ahk = 0;
    if constexpr (KSPLIT && AH) ahk = kp * (K >> 4);
    const u16* A0 = A + (size_t)(m0 + (ATHIN ? (r0 & 63) : r0)) * K + kofs + c0 * 8;
    const u16* A1 = A + (size_t)(m0 + r1) * K + kofs + c1 * 8;  // ALD==2 only
    const u16* B0 = BT + (size_t)(n0 + r0) * K + kofs + c0 * 8;
    const u16* B1 = BT + (size_t)(n0 + r1) * K + kofs + c1 * 8; // BLD==2 only
    const u16* Abase = nullptr;
    if constexpr (AH) {
        int m = m0 + r0;
        Abase = A + ((size_t)(m >> 10) * 12288 + (m & 1023)) * 64;
    }

    int nk = K >> 5;
    if constexpr (KSPLIT) nk >>= 1;

    f32x4 acc[MI][NJ];
    for (int i = 0; i < MI; i++)
        for (int j = 0; j < NJ; j++)
            for (int r = 0; r < 4; r++) acc[i][j][r] = 0.0f;

    for (int s = 0; s < NS - 1; s++) {
        if constexpr (AH) {
            int col8 = ahk + s * 4 + c0;
            GLOAD_LDS16(Abase + (col8 >> 3) * 65536 + (col8 & 7) * 8, &As[s][e0 * 8]);
        } else if constexpr (ATHIN) {
            if (wave < 4) GLOAD_LDS16(A0 + s * 32, &As[s][e0 * 8]);  // wave-uniform guard
        } else {
            GLOAD_LDS16(A0 + s * 32, &As[s][e0 * 8]);
            if constexpr (ALD == 2) GLOAD_LDS16(A1 + s * 32, &As[s][e1 * 8]);
        }
        GLOAD_LDS16(B0 + s * 32, &Bs[s][e0 * 8]);
        if constexpr (BLD == 2) GLOAD_LDS16(B1 + s * 32, &Bs[s][e1 * 8]);
    }

    for (int kb = 0; kb < nk; kb += NS) {
#pragma unroll
        for (int s = 0; s < NS; s++) {
            int k = kb + s;
            if constexpr (ATHIN) {
                // per-wave counted vmcnt: waves 0-3 issue 2 loads/step, waves 4-7 issue 1
                if (wave < 4) asm volatile("s_waitcnt vmcnt(4)" ::: "memory");
                else          asm volatile("s_waitcnt vmcnt(2)" ::: "memory");
            }
            else if constexpr (VC == 6) asm volatile("s_waitcnt vmcnt(6)" ::: "memory");
            else if constexpr (VC == 4) asm volatile("s_waitcnt vmcnt(4)" ::: "memory");
            else if constexpr (VC == 3) asm volatile("s_waitcnt vmcnt(3)" ::: "memory");
            else if constexpr (VC == 2) asm volatile("s_waitcnt vmcnt(2)" ::: "memory");
            else                        asm volatile("s_waitcnt vmcnt(0)" ::: "memory");
            asm volatile("s_barrier" ::: "memory");
            {
                int ks = k + NS - 1 < nk ? k + NS - 1 : nk - 1;  // clamped: uniform in-flight count
                int stage = (s + NS - 1) % NS;  // s constant under unroll -> folds
                if constexpr (AH) {
                    int col8 = ahk + ks * 4 + c0;
                    GLOAD_LDS16(Abase + (col8 >> 3) * 65536 + (col8 & 7) * 8, &As[stage][e0 * 8]);
                } else if constexpr (ATHIN) {
                    if (wave < 4) GLOAD_LDS16(A0 + ks * 32, &As[stage][e0 * 8]);
                } else {
                    GLOAD_LDS16(A0 + ks * 32, &As[stage][e0 * 8]);
                    if constexpr (ALD == 2) GLOAD_LDS16(A1 + ks * 32, &As[stage][e1 * 8]);
                }
                GLOAD_LDS16(B0 + ks * 32, &Bs[stage][e0 * 8]);
                if constexpr (BLD == 2) GLOAD_LDS16(B1 + ks * 32, &Bs[stage][e1 * 8]);
            }
            const u16* as = As[s];
            const u16* bs = Bs[s];
            bf16x8 afr[MI], bfr[NJ];
            for (int i = 0; i < MI; i++)
                afr[i] = *reinterpret_cast<const bf16x8*>(&as[(wr + i * 16 + ln) * 32 + sw * 8]);
            for (int j = 0; j < NJ; j++)
                bfr[j] = *reinterpret_cast<const bf16x8*>(&bs[(wc + j * 16 + ln) * 32 + sw * 8]);
            for (int i = 0; i < MI; i++)
                for (int j = 0; j < NJ; j++)
                    acc[i][j] = MFMA(afr[i], bfr[j], acc[i][j]);
        }
    }

    for (int i = 0; i < MI; i++) {
        for (int j = 0; j < NJ; j++) {
            int col = n0 + wc + j * 16 + ln;
            for (int r = 0; r < 4; r++) {
                int row = m0 + wr + i * 16 + quad * 4 + r;
                size_t idx = (size_t)row * N + col;
                float v = acc[i][j][r];
                if constexpr (EPI == 1) {
                    if constexpr (KSPLIT) {
                        if (kp == 0) outF[idx] = resid[idx] + v;
                        else reinterpret_cast<float*>(outB)[idx] = v;
                    } else {
                        outF[idx] = resid[idx] + v;
                    }
                } else if constexpr (EPI == 2) {
                    outB[idx] = f2bf(fast_gelu(v + bias[col]));
                } else if constexpr (EPI == 3) {
                    if constexpr (KSPLIT) {
                        if (kp == 0) outF[idx] = resid[idx] + v + bias[col];
                        else reinterpret_cast<float*>(outB)[idx] = v;
                    } else {
                        outF[idx] = resid[idx] + v + bias[col];
                    }
                } else {
                    // 0.125 * log2(e): Q scores land in log2 domain for exp2 softmax
                    outB[idx] = f2bf(col < 768 ? v * 0.18033688011112042f : v);
                }
            }
        }
    }
}

// ---------------- flash-style attention (ctx = softmax @ K), Q prescaled to log2 domain ----------------
__global__ __launch_bounds__(256) void attention_k(const u16* __restrict__ QB, int ldq,
                                                   const u16* __restrict__ KH,
                                                   const u16* __restrict__ KHT,
                                                   u16* __restrict__ CTXH) {
    __shared__ __align__(16) u16 Ks[64 * 72];   // [m'][d]
    __shared__ __align__(16) u16 KsT[64 * 72];  // [d][m']
    __shared__ __align__(16) u16 Pl[4][16 * 72];
    int bh = blockIdx.y;
    int b = bh / 12, n = bh % 12;
    int l0 = blockIdx.x * 64;
    int t = threadIdx.x, wave = t >> 6, lane = t & 63;
    int ln = lane & 15, quad = lane >> 4;
    int lw = l0 + wave * 16;

    // Q A-fragments (strided gather, once per block); Q already scaled by 0.125*log2e
    bf16x8 a0, a1;
    {
        union { u16 u[8]; bf16x8 v; } q0, q1;
        const u16* qrow = QB + (size_t)(b * 1024 + lw + ln) * ldq + n;
        for (int j = 0; j < 8; j++) {
            q0.u[j] = qrow[(quad * 8 + j) * 12];
            q1.u[j] = qrow[(32 + quad * 8 + j) * 12];
        }
        a0 = q0.v; a1 = q1.v;
    }

    f32x4 o[4];
    for (int dt = 0; dt < 4; dt++)
        for (int r = 0; r < 4; r++) o[dt][r] = 0.0f;
    float lst[4];
    for (int r = 0; r < 4; r++) lst[r] = 0.0f;

    const u16* Kbase  = KH  + (size_t)bh * 65536;
    const u16* KTbase = KHT + (size_t)bh * 65536;  // [d][m], 64 rows x 1024
    int mi = t & 63, ds = (t >> 6) * 16;

    uint4 kva = *reinterpret_cast<const uint4*>(&Kbase[(size_t)mi * 64 + ds]);
    uint4 kvb = *reinterpret_cast<const uint4*>(&Kbase[(size_t)mi * 64 + ds + 8]);
    uint4 kta = *reinterpret_cast<const uint4*>(&KTbase[(size_t)mi * 1024 + ds]);
    uint4 ktb = *reinterpret_cast<const uint4*>(&KTbase[(size_t)mi * 1024 + ds + 8]);

    for (int mb = 0; mb < 16; mb++) {
        __syncthreads();
        *reinterpret_cast<uint4*>(&Ks[mi * 72 + ds]) = kva;
        *reinterpret_cast<uint4*>(&Ks[mi * 72 + ds + 8]) = kvb;
        *reinterpret_cast<uint4*>(&KsT[mi * 72 + ds]) = kta;
        *reinterpret_cast<uint4*>(&KsT[mi * 72 + ds + 8]) = ktb;
        __syncthreads();

        {
            int mnext = (mb + 1 < 16 ? mb + 1 : 15) * 64;
            kva = *reinterpret_cast<const uint4*>(&Kbase[(size_t)(mnext + mi) * 64 + ds]);
            kvb = *reinterpret_cast<const uint4*>(&Kbase[(size_t)(mnext + mi) * 64 + ds + 8]);
            kta = *reinterpret_cast<const uint4*>(&KTbase[(size_t)mi * 1024 + mnext + ds]);
            ktb = *reinterpret_cast<const uint4*>(&KTbase[(size_t)mi * 1024 + mnext + ds + 8]);
        }

        f32x4 st[4];
        for (int nt = 0; nt < 4; nt++) {
            bf16x8 bk0 = *reinterpret_cast<bf16x8*>(&Ks[(nt * 16 + ln) * 72 + quad * 8]);
            bf16x8 bk1 = *reinterpret_cast<bf16x8*>(&Ks[(nt * 16 + ln) * 72 + 32 + quad * 8]);
            f32x4 z;
            for (int r = 0; r < 4; r++) z[r] = 0.0f;
            z = MFMA(a0, bk0, z);
            st[nt] = MFMA(a1, bk1, z);
        }

        // softmax numerator: p = exp2(st) (st already includes 1/8 * log2e); no max, no clamp
        for (int r = 0; r < 4; r++) {
            int row = quad * 4 + r;
            float psum = 0.0f;
            for (int nt = 0; nt < 4; nt++) {
                float p = exp2f(st[nt][r]);
                psum += p;
                Pl[wave][row * 72 + nt * 16 + ln] = f2bf_trunc(p);
            }
            lst[r] += psum;
        }

        // PV: O += P(16x64) @ K(64x64)   (Pl wave-private: no barrier)
        bf16x8 pf0 = *reinterpret_cast<bf16x8*>(&Pl[wave][ln * 72 + quad * 8]);
        bf16x8 pf1 = *reinterpret_cast<bf16x8*>(&Pl[wave][ln * 72 + 32 + quad * 8]);
        for (int dt = 0; dt < 4; dt++) {
            bf16x8 bk0 = *reinterpret_cast<bf16x8*>(&KsT[(dt * 16 + ln) * 72 + quad * 8]);
            bf16x8 bk1 = *reinterpret_cast<bf16x8*>(&KsT[(dt * 16 + ln) * 72 + 32 + quad * 8]);
            o[dt] = MFMA(pf0, bk0, o[dt]);
            o[dt] = MFMA(pf1, bk1, o[dt]);
        }
    }

    for (int r = 0; r < 4; r++)
        for (int off = 1; off < 16; off <<= 1) lst[r] += __shfl_xor(lst[r], off, 64);

    u16* out = CTXH + (size_t)bh * 65536;
    for (int r = 0; r < 4; r++) {
        float inv = 1.0f / lst[r];
        int row = lw + quad * 4 + r;
        for (int dt = 0; dt < 4; dt++)
            out[(size_t)row * 64 + dt * 16 + ln] = f2bf(o[dt][r] * inv);
    }
}

// ---------------- layernorm over 768, one block per row; optional second input ----------------
__global__ __launch_bounds__(256) void layernorm_k(const float* __restrict__ in,
                                                   float* __restrict__ outF,
                                                   u16* __restrict__ outB,
                                                   const float* __restrict__ g,
                                                   const float* __restrict__ be,
                                                   const float* __restrict__ in2) {
    __shared__ float red[8];
    int row = blockIdx.x;
    int t = threadIdx.x;
    const float* p = in + (size_t)row * 768;
    float v0 = p[t], v1 = p[t + 256], v2 = p[t + 512];
    if (in2) {
        const float* p2 = in2 + (size_t)row * 768;
        v0 += p2[t]; v1 += p2[t + 256]; v2 += p2[t + 512];
    }
    float s = v0 + v1 + v2;
    float ss = v0 * v0 + v1 * v1 + v2 * v2;
    for (int off = 32; off >= 1; off >>= 1) {
        s += __shfl_xor(s, off, 64);
        ss += __shfl_xor(ss, off, 64);
    }
    int wave = t >> 6, lane = t & 63;
    if (lane == 0) { red[wave] = s; red[4 + wave] = ss; }
    __syncthreads();
    float S = red[0] + red[1] + red[2] + red[3];
    float SS = red[4] + red[5] + red[6] + red[7];
    float mean = S * (1.0f / 768.0f);
    float var = SS * (1.0f / 768.0f) - mean * mean;
    float rstd = rsqrtf(var + 1e-5f);
    float o0 = (v0 - mean) * rstd * g[t] + be[t];
    float o1 = (v1 - mean) * rstd * g[t + 256] + be[t + 256];
    float o2 = (v2 - mean) * rstd * g[t + 512] + be[t + 512];
    float* q = outF + (size_t)row * 768;
    q[t] = o0; q[t + 256] = o1; q[t + 512] = o2;
    if (outB) {
        u16* qb = outB + (size_t)row * 768;
        qb[t] = f2bf(o0); qb[t + 256] = f2bf(o1); qb[t + 512] = f2bf(o2);
    }
}

extern "C" void kernel_launch(void* const* d_in, const int* in_sizes, int n_in,
                              void* d_out, int out_size, void* d_ws, size_t ws_size,
                              hipStream_t stream) {
    const float* x   = (const float*)d_in[0];
    const float* Wq  = (const float*)d_in[1];
    const float* Wk  = (const float*)d_in[2];
    // d_in[3] = Wv — dead code in the reference, skipped.
    const float* Wo  = (const float*)d_in[4];
    const float* W1  = (const float*)d_in[5];
    const float* b1  = (const float*)d_in[6];
    const float* W2  = (const float*)d_in[7];
    const float* b2  = (const float*)d_in[8];
    const float* g1  = (const float*)d_in[9];
    const float* be1 = (const float*)d_in[10];
    const float* g2  = (const float*)d_in[11];
    const float* be2 = (const float*)d_in[12];
    float* out = (float*)d_out;

    const int S = 8192, H = 768, MLP4 = 3072, H2 = 1536;

    char* ws = (char*)d_ws;
    u16* XB   = (u16*)ws;  ws += (size_t)S * H * 2;      // reused as CTXH
    u16* WQKT = (u16*)ws;  ws += (size_t)H2 * H * 2;
    u16* WOT  = (u16*)ws;  ws += (size_t)H * H * 2;      // k-permuted
    u16* W1T  = (u16*)ws;  ws += (size_t)H * MLP4 * 2;
    u16* W2T  = (u16*)ws;  ws += (size_t)H * MLP4 * 2;
    u16* QKB  = (u16*)ws;  ws += (size_t)S * H2 * 2;     // Q (log2-prescaled) | K, row-major
    u16* KH   = (u16*)ws;  ws += (size_t)S * H * 2;      // K head-major
    float* Y  = (float*)ws; ws += (size_t)S * H * 4;
    u16* HB   = (u16*)ws;  ws += (size_t)S * MLP4 * 2;

    u16* CTXH = XB;          // after QK gemm, XB is dead
    u16* X1B  = QKB;         // Q half, dead after attention
    u16* KHT  = HB;          // HB dead until W1 gemm; holds K transposed (12.6 MB < 50 MB)

    // 1. fused prep: x cast + all weight transposes
    prep_k<<<4608, 256, 0, stream>>>(x, Wq, Wk, Wo, W1, W2, XB, WQKT, WOT, W1T, W2T);

    // 2. [Q|K] = X [Wq|Wk]  — 512-thread 8-wave variant
    gemm_bt_k<4, 128, false, 0, false, 512><<<12 * 64, 512, 0, stream>>>(XB, WQKT, S, H2, H, 12, nullptr, QKB, nullptr, nullptr);

    // 3. attention (K repacked head-major + transposed; ctx stays head-major in CTXH)
    head_pack_k<<<dim3(64, 8), 256, 0, stream>>>(QKB + H, H2, KH, KHT);
    attention_k<<<dim3(16, 96), 256, 0, stream>>>(QKB, H2, KH, KHT, CTXH);

    // 4. y = x + ctx Wo ; x1 = LN1(y) in-place + bf16 copy  (round-3 verified config)
    gemm_bt_k<1, 64, true><<<6 * 128, 256, 0, stream>>>(CTXH, WOT, S, H, H, 6, Y, nullptr, x, nullptr);
    layernorm_k<<<S, 256, 0, stream>>>(Y, Y, X1B, g1, be1, nullptr);

    // 5. h = gelu(x1 W1 + b1) ; y2 = x1 + h W2 + b2 ; out = LN2(y2)
    //    W1: 512-thread 8-wave. W2: TM=128 fat tile, NSO=4 (VC=4, 2-step cover),
    //    grid 384 = half the block count (144 block-steps/CU vs 288) — r15 proved
    //    per-block-step cost is occupancy-invariant, so fewer step-slots is the lever.
    gemm_bt_k<2, 128, false, 0, false, 512><<<24 * 64, 512, 0, stream>>>(X1B, W1T, S, MLP4, H, 24, nullptr, HB, nullptr, b1);
    gemm_bt_k<3, 128, false, 4, false, 512><<<6 * 64, 512, 0, stream>>>(HB, W2T, S, H, MLP4, 6, Y, nullptr, Y, b2);
    layernorm_k<<<S, 256, 0, stream>>>(Y, out, nullptr, g2, be2, nullptr);
}

// Round 20
// 372.010 us; speedup vs baseline: 1.1264x; 1.0048x over previous
//
#include <hip/hip_runtime.h>
#include <math.h>

typedef unsigned short u16;
typedef unsigned int u32;
typedef short bf16x8 __attribute__((ext_vector_type(8)));
typedef float f32x4 __attribute__((ext_vector_type(4)));

#define MFMA(a, b, c) __builtin_amdgcn_mfma_f32_16x16x32_bf16((a), (b), (c), 0, 0, 0)

// async global->LDS, 16B per lane; LDS dest = wave-uniform base + lane*16
#define GLOAD_LDS16(g, l)                                                              \
    __builtin_amdgcn_global_load_lds((const __attribute__((address_space(1))) void*)(g), \
                                     (__attribute__((address_space(3))) void*)(l), 16, 0, 0)

__device__ __forceinline__ u16 f2bf(float f) {
    u32 u = __float_as_uint(f);
    u32 r = (u + 0x7fffu + ((u >> 16) & 1u)) >> 16;
    return (u16)r;
}

__device__ __forceinline__ u16 f2bf_trunc(float f) {  // truncating bf16 (1 VALU op)
    return (u16)(__float_as_uint(f) >> 16);
}

// tanh-form GELU via native exp/rcp
__device__ __forceinline__ float fast_gelu(float z) {
    float u = fminf(1.5957691216f * z * (1.0f + 0.044715f * z * z), 80.0f);
    float e = __expf(u);
    float r = __builtin_amdgcn_rcpf(e + 1.0f);
    return z * e * r;
}

// ================= fused prep: x cast + all weight transposes, one dispatch =================
__device__ void dev_xcast(const float* __restrict__ in, u16* __restrict__ out, int blk) {
    size_t i = ((size_t)blk * 256 + threadIdx.x) * 8;
    const float4* p = reinterpret_cast<const float4*>(in + i);
    float4 a = p[0], b = p[1];
    union { u16 u[8]; uint4 v; } o;
    o.u[0] = f2bf(a.x); o.u[1] = f2bf(a.y); o.u[2] = f2bf(a.z); o.u[3] = f2bf(a.w);
    o.u[4] = f2bf(b.x); o.u[5] = f2bf(b.y); o.u[6] = f2bf(b.z); o.u[7] = f2bf(b.w);
    *reinterpret_cast<uint4*>(out + i) = o.v;
}

__device__ void dev_transpose(const float* __restrict__ in, u16* __restrict__ out,
                              int K, int N, int bx, int by, float* tile /* [64][65] */) {
    int k0 = by * 64, n0 = bx * 64;
    int t = threadIdx.x;
    for (int p = 0; p < 16; p++) {
        int idx = t + p * 256;
        int r = idx >> 6, c = idx & 63;
        tile[r * 65 + c] = in[(size_t)(k0 + r) * N + n0 + c];
    }
    __syncthreads();
    for (int p = 0; p < 16; p++) {
        int idx = t + p * 256;
        int nr = idx >> 6, nc = idx & 63;
        out[(size_t)(n0 + nr) * K + k0 + nc] = f2bf(tile[nc * 65 + nr]);
    }
}

// Wo transpose with k-permute: out[col][n*64+d] = Wo[d*12+n][col]
__device__ void dev_wo(const float* __restrict__ in, u16* __restrict__ out,
                       int bx, int by, float* tile /* [96][65] */) {
    int k0 = by * 96, n0 = bx * 64;
    int t = threadIdx.x;
    for (int p = 0; p < 24; p++) {
        int idx = t + p * 256;
        int r = idx >> 6, c = idx & 63;
        tile[r * 65 + c] = in[(size_t)(k0 + r) * 768 + n0 + c];
    }
    __syncthreads();
    for (int p = 0; p < 3; p++) {
        int idx = t + p * 256;  // (col c)*12 + n
        int c = idx / 12, n = idx % 12;
        union { u16 u[8]; uint4 v; } o;
        for (int j = 0; j < 8; j++) o.u[j] = f2bf(tile[(j * 12 + n) * 65 + c]);
        *reinterpret_cast<uint4*>(&out[(size_t)(n0 + c) * 768 + n * 64 + by * 8]) = o.v;
    }
}

__global__ __launch_bounds__(256) void prep_k(const float* __restrict__ x,
                                              const float* __restrict__ Wq,
                                              const float* __restrict__ Wk,
                                              const float* __restrict__ Wo,
                                              const float* __restrict__ W1,
                                              const float* __restrict__ W2,
                                              u16* __restrict__ XB,
                                              u16* __restrict__ WQKT,
                                              u16* __restrict__ WOT,
                                              u16* __restrict__ W1T,
                                              u16* __restrict__ W2T) {
    __shared__ float tile[96 * 65];
    int bid = blockIdx.x;
    if (bid < 3072) {
        dev_xcast(x, XB, bid);
    } else if (bid < 3216) {
        int b = bid - 3072; dev_transpose(Wq, WQKT, 768, 768, b % 12, b / 12, tile);
    } else if (bid < 3360) {
        int b = bid - 3216; dev_transpose(Wk, WQKT + (size_t)768 * 768, 768, 768, b % 12, b / 12, tile);
    } else if (bid < 3456) {
        int b = bid - 3360; dev_wo(Wo, WOT, b % 12, b / 12, tile);
    } else if (bid < 4032) {
        int b = bid - 3456; dev_transpose(W1, W1T, 768, 3072, b % 48, b / 48, tile);
    } else {
        int b = bid - 4032; dev_transpose(W2, W2T, 3072, 768, b % 12, b / 12, tile);
    }
}

// ---------------- head pack: in (S x ld, col base pre-offset) -> KH (96 x 1024 x 64) ----------------
// Also emits KHT (96 x 64 x 1024): KHT[head][d][m] = K[b][m][d*12+n].
__global__ __launch_bounds__(256) void head_pack_k(const u16* __restrict__ in, int ld,
                                                   u16* __restrict__ out,
                                                   u16* __restrict__ outT) {
    __shared__ u16 tile[16 * 768];
    int b = blockIdx.y;
    int l0 = blockIdx.x * 16;
    int t = threadIdx.x;
    for (int p = 0; p < 6; p++) {
        int c = t + p * 256;
        int li = c / 96, dc = c % 96;
        *reinterpret_cast<uint4*>(&tile[li * 768 + dc * 8]) =
            *reinterpret_cast<const uint4*>(&in[(size_t)(b * 1024 + l0 + li) * ld + dc * 8]);
    }
    __syncthreads();
    for (int p = 0; p < 6; p++) {
        int c = t + p * 256;
        int n = c >> 7, rem = c & 127, li = rem >> 3, k8 = rem & 7;
        union { u16 u[8]; uint4 v; } o;
        for (int j = 0; j < 8; j++) o.u[j] = tile[li * 768 + (k8 * 8 + j) * 12 + n];
        *reinterpret_cast<uint4*>(&out[(size_t)((b * 12 + n) * 1024 + l0 + li) * 64 + k8 * 8]) = o.v;
    }
    // transposed copy: 6 passes x 256 threads cover 12 heads x 64 d x 2 halves (8 m each)
    for (int p = 0; p < 6; p++) {
        int c = t + p * 256;                 // 0..1535
        int n = c >> 7;                      // head 0..11
        int rem = c & 127;
        int d = rem >> 1;                    // 0..63
        int half = rem & 1;                  // m-offset 0 or 8
        union { u16 u[8]; uint4 v; } o;
        for (int j = 0; j < 8; j++) o.u[j] = tile[(half * 8 + j) * 768 + d * 12 + n];
        *reinterpret_cast<uint4*>(
            &outT[((size_t)(b * 12 + n) * 64 + d) * 1024 + l0 + half * 8]) = o.v;
    }
}

// ---------------- GEMM: C(MxN) = A(MxK bf16) @ BT(NxK bf16)^T ----------------
// TM x 128 tile, NS-stage pipeline, ONE raw s_barrier per K-step, counted per-wave vmcnt.
// NT=256: 4 waves.  NT=512 + TM=128: 8 waves, 64x32 subtiles.
// NT=512 + TM=64 (ATHIN): 8 waves, 32x32 subtiles; A staged by waves 0-3 only.
// W2 & Wo use TM=128/NT=512/NSO=4: halves block count — r19 A/B confirmed the
// per-block-step cost is fixed & occupancy-invariant, so fewer step-slots wins
// (W2 78 -> <74 us). NSO=4 gives VC=4 (2-step prefetch cover > HBM latency).
// AH: A is CTXH [b*12+n][l][64], logical k = n*64+d (works for any TM; BT rows permuted).
// EPI 1: outF = resid + acc;  2: outB = bf16(gelu(acc + bias[col]));
// EPI 3: outF = resid + acc + bias[col];
// EPI 4: outB = bf16(acc * (col<768 ? 0.125*log2e : 1))  [QK proj; Q in log2-domain]
template <int EPI, int TM, bool AH = false, int NSO = 0, bool KSPLIT = false, int NT = 256>
__global__ __launch_bounds__(NT) void gemm_bt_k(const u16* __restrict__ A,
                                                const u16* __restrict__ BT,
                                                int M, int N, int K, int NBX,
                                                float* __restrict__ outF,
                                                u16* __restrict__ outB,
                                                const float* __restrict__ resid,
                                                const float* __restrict__ bias) {
    constexpr int NS = NSO ? NSO : ((TM == 64) ? 4 : 3);
    constexpr int WN = (NT == 512) ? 4 : 2;          // waves along N
    constexpr int MI = (TM / 2) / 16;                // A-frag repeats per wave
    constexpr int NJ = (128 / WN) / 16;              // B-frag repeats per wave
    constexpr bool ATHIN = (TM == 64 && NT == 512);  // A tile smaller than thread count
    constexpr int ALD = (TM == 128 && NT == 256) ? 2 : 1;  // A loads / thread / step
    constexpr int BLD = (NT == 256) ? 2 : 1;               // B loads / thread / step
    constexpr int LPS = ALD + BLD;
    constexpr int VC = LPS * (NS - 2);               // counted vmcnt at the wait point
    __shared__ __align__(16) u16 As[NS][TM * 32];
    __shared__ __align__(16) u16 Bs[NS][128 * 32];

    int L = blockIdx.x;
    int kp = 0;
    if constexpr (KSPLIT) {
        int half = gridDim.x >> 1;
        if (L >= half) { kp = 1; L -= half; }
    }
    int bx = (L >> 3) % NBX;
    int by = (L / (8 * NBX)) * 8 + (L & 7);
    int m0 = by * TM, n0 = bx * 128;

    int t = threadIdx.x;
    int wave = t >> 6, lane = t & 63;
    int wr = (wave / WN) * (TM / 2), wc = (wave % WN) * (128 / WN);
    int ln = lane & 15, quad = lane >> 4;
    int sw = quad ^ ((ln >> 1) & 3);

    int e0 = t, e1 = t + 256;                        // e1 only used when NT==256
    int r0 = e0 >> 2, c0 = (e0 & 3) ^ ((r0 >> 1) & 3);
    int r1 = e1 >> 2, c1 = (e1 & 3) ^ ((r1 >> 1) & 3);
    int kofs = 0;
    if constexpr (KSPLIT) kofs = kp * (K >> 1);
    int ahk = 0;
    if constexpr (KSPLIT && AH) ahk = kp * (K >> 4);
    const u16* A0 = A + (size_t)(m0 + (ATHIN ? (r0 & 63) : r0)) * K + kofs + c0 * 8;
    const u16* A1 = A + (size_t)(m0 + r1) * K + kofs + c1 * 8;  // ALD==2 only
    const u16* B0 = BT + (size_t)(n0 + r0) * K + kofs + c0 * 8;
    const u16* B1 = BT + (size_t)(n0 + r1) * K + kofs + c1 * 8; // BLD==2 only
    const u16* Abase = nullptr;
    if constexpr (AH) {
        int m = m0 + r0;
        Abase = A + ((size_t)(m >> 10) * 12288 + (m & 1023)) * 64;
    }

    int nk = K >> 5;
    if constexpr (KSPLIT) nk >>= 1;

    f32x4 acc[MI][NJ];
    for (int i = 0; i < MI; i++)
        for (int j = 0; j < NJ; j++)
            for (int r = 0; r < 4; r++) acc[i][j][r] = 0.0f;

    for (int s = 0; s < NS - 1; s++) {
        if constexpr (AH) {
            int col8 = ahk + s * 4 + c0;
            GLOAD_LDS16(Abase + (col8 >> 3) * 65536 + (col8 & 7) * 8, &As[s][e0 * 8]);
        } else if constexpr (ATHIN) {
            if (wave < 4) GLOAD_LDS16(A0 + s * 32, &As[s][e0 * 8]);  // wave-uniform guard
        } else {
            GLOAD_LDS16(A0 + s * 32, &As[s][e0 * 8]);
            if constexpr (ALD == 2) GLOAD_LDS16(A1 + s * 32, &As[s][e1 * 8]);
        }
        GLOAD_LDS16(B0 + s * 32, &Bs[s][e0 * 8]);
        if constexpr (BLD == 2) GLOAD_LDS16(B1 + s * 32, &Bs[s][e1 * 8]);
    }

    for (int kb = 0; kb < nk; kb += NS) {
#pragma unroll
        for (int s = 0; s < NS; s++) {
            int k = kb + s;
            if constexpr (ATHIN) {
                // per-wave counted vmcnt: waves 0-3 issue 2 loads/step, waves 4-7 issue 1
                if (wave < 4) asm volatile("s_waitcnt vmcnt(4)" ::: "memory");
                else          asm volatile("s_waitcnt vmcnt(2)" ::: "memory");
            }
            else if constexpr (VC == 6) asm volatile("s_waitcnt vmcnt(6)" ::: "memory");
            else if constexpr (VC == 4) asm volatile("s_waitcnt vmcnt(4)" ::: "memory");
            else if constexpr (VC == 3) asm volatile("s_waitcnt vmcnt(3)" ::: "memory");
            else if constexpr (VC == 2) asm volatile("s_waitcnt vmcnt(2)" ::: "memory");
            else                        asm volatile("s_waitcnt vmcnt(0)" ::: "memory");
            asm volatile("s_barrier" ::: "memory");
            {
                int ks = k + NS - 1 < nk ? k + NS - 1 : nk - 1;  // clamped: uniform in-flight count
                int stage = (s + NS - 1) % NS;  // s constant under unroll -> folds
                if constexpr (AH) {
                    int col8 = ahk + ks * 4 + c0;
                    GLOAD_LDS16(Abase + (col8 >> 3) * 65536 + (col8 & 7) * 8, &As[stage][e0 * 8]);
                } else if constexpr (ATHIN) {
                    if (wave < 4) GLOAD_LDS16(A0 + ks * 32, &As[stage][e0 * 8]);
                } else {
                    GLOAD_LDS16(A0 + ks * 32, &As[stage][e0 * 8]);
                    if constexpr (ALD == 2) GLOAD_LDS16(A1 + ks * 32, &As[stage][e1 * 8]);
                }
                GLOAD_LDS16(B0 + ks * 32, &Bs[stage][e0 * 8]);
                if constexpr (BLD == 2) GLOAD_LDS16(B1 + ks * 32, &Bs[stage][e1 * 8]);
            }
            const u16* as = As[s];
            const u16* bs = Bs[s];
            bf16x8 afr[MI], bfr[NJ];
            for (int i = 0; i < MI; i++)
                afr[i] = *reinterpret_cast<const bf16x8*>(&as[(wr + i * 16 + ln) * 32 + sw * 8]);
            for (int j = 0; j < NJ; j++)
                bfr[j] = *reinterpret_cast<const bf16x8*>(&bs[(wc + j * 16 + ln) * 32 + sw * 8]);
            for (int i = 0; i < MI; i++)
                for (int j = 0; j < NJ; j++)
                    acc[i][j] = MFMA(afr[i], bfr[j], acc[i][j]);
        }
    }

    for (int i = 0; i < MI; i++) {
        for (int j = 0; j < NJ; j++) {
            int col = n0 + wc + j * 16 + ln;
            for (int r = 0; r < 4; r++) {
                int row = m0 + wr + i * 16 + quad * 4 + r;
                size_t idx = (size_t)row * N + col;
                float v = acc[i][j][r];
                if constexpr (EPI == 1) {
                    if constexpr (KSPLIT) {
                        if (kp == 0) outF[idx] = resid[idx] + v;
                        else reinterpret_cast<float*>(outB)[idx] = v;
                    } else {
                        outF[idx] = resid[idx] + v;
                    }
                } else if constexpr (EPI == 2) {
                    outB[idx] = f2bf(fast_gelu(v + bias[col]));
                } else if constexpr (EPI == 3) {
                    if constexpr (KSPLIT) {
                        if (kp == 0) outF[idx] = resid[idx] + v + bias[col];
                        else reinterpret_cast<float*>(outB)[idx] = v;
                    } else {
                        outF[idx] = resid[idx] + v + bias[col];
                    }
                } else {
                    // 0.125 * log2(e): Q scores land in log2 domain for exp2 softmax
                    outB[idx] = f2bf(col < 768 ? v * 0.18033688011112042f : v);
                }
            }
        }
    }
}

// ---------------- flash-style attention (ctx = softmax @ K), Q prescaled to log2 domain ----------------
__global__ __launch_bounds__(256) void attention_k(const u16* __restrict__ QB, int ldq,
                                                   const u16* __restrict__ KH,
                                                   const u16* __restrict__ KHT,
                                                   u16* __restrict__ CTXH) {
    __shared__ __align__(16) u16 Ks[64 * 72];   // [m'][d]
    __shared__ __align__(16) u16 KsT[64 * 72];  // [d][m']
    __shared__ __align__(16) u16 Pl[4][16 * 72];
    int bh = blockIdx.y;
    int b = bh / 12, n = bh % 12;
    int l0 = blockIdx.x * 64;
    int t = threadIdx.x, wave = t >> 6, lane = t & 63;
    int ln = lane & 15, quad = lane >> 4;
    int lw = l0 + wave * 16;

    // Q A-fragments (strided gather, once per block); Q already scaled by 0.125*log2e
    bf16x8 a0, a1;
    {
        union { u16 u[8]; bf16x8 v; } q0, q1;
        const u16* qrow = QB + (size_t)(b * 1024 + lw + ln) * ldq + n;
        for (int j = 0; j < 8; j++) {
            q0.u[j] = qrow[(quad * 8 + j) * 12];
            q1.u[j] = qrow[(32 + quad * 8 + j) * 12];
        }
        a0 = q0.v; a1 = q1.v;
    }

    f32x4 o[4];
    for (int dt = 0; dt < 4; dt++)
        for (int r = 0; r < 4; r++) o[dt][r] = 0.0f;
    float lst[4];
    for (int r = 0; r < 4; r++) lst[r] = 0.0f;

    const u16* Kbase  = KH  + (size_t)bh * 65536;
    const u16* KTbase = KHT + (size_t)bh * 65536;  // [d][m], 64 rows x 1024
    int mi = t & 63, ds = (t >> 6) * 16;

    uint4 kva = *reinterpret_cast<const uint4*>(&Kbase[(size_t)mi * 64 + ds]);
    uint4 kvb = *reinterpret_cast<const uint4*>(&Kbase[(size_t)mi * 64 + ds + 8]);
    uint4 kta = *reinterpret_cast<const uint4*>(&KTbase[(size_t)mi * 1024 + ds]);
    uint4 ktb = *reinterpret_cast<const uint4*>(&KTbase[(size_t)mi * 1024 + ds + 8]);

    for (int mb = 0; mb < 16; mb++) {
        __syncthreads();
        *reinterpret_cast<uint4*>(&Ks[mi * 72 + ds]) = kva;
        *reinterpret_cast<uint4*>(&Ks[mi * 72 + ds + 8]) = kvb;
        *reinterpret_cast<uint4*>(&KsT[mi * 72 + ds]) = kta;
        *reinterpret_cast<uint4*>(&KsT[mi * 72 + ds + 8]) = ktb;
        __syncthreads();

        {
            int mnext = (mb + 1 < 16 ? mb + 1 : 15) * 64;
            kva = *reinterpret_cast<const uint4*>(&Kbase[(size_t)(mnext + mi) * 64 + ds]);
            kvb = *reinterpret_cast<const uint4*>(&Kbase[(size_t)(mnext + mi) * 64 + ds + 8]);
            kta = *reinterpret_cast<const uint4*>(&KTbase[(size_t)mi * 1024 + mnext + ds]);
            ktb = *reinterpret_cast<const uint4*>(&KTbase[(size_t)mi * 1024 + mnext + ds + 8]);
        }

        f32x4 st[4];
        for (int nt = 0; nt < 4; nt++) {
            bf16x8 bk0 = *reinterpret_cast<bf16x8*>(&Ks[(nt * 16 + ln) * 72 + quad * 8]);
            bf16x8 bk1 = *reinterpret_cast<bf16x8*>(&Ks[(nt * 16 + ln) * 72 + 32 + quad * 8]);
            f32x4 z;
            for (int r = 0; r < 4; r++) z[r] = 0.0f;
            z = MFMA(a0, bk0, z);
            st[nt] = MFMA(a1, bk1, z);
        }

        // softmax numerator: p = exp2(st) (st already includes 1/8 * log2e); no max, no clamp
        for (int r = 0; r < 4; r++) {
            int row = quad * 4 + r;
            float psum = 0.0f;
            for (int nt = 0; nt < 4; nt++) {
                float p = exp2f(st[nt][r]);
                psum += p;
                Pl[wave][row * 72 + nt * 16 + ln] = f2bf_trunc(p);
            }
            lst[r] += psum;
        }

        // PV: O += P(16x64) @ K(64x64)   (Pl wave-private: no barrier)
        bf16x8 pf0 = *reinterpret_cast<bf16x8*>(&Pl[wave][ln * 72 + quad * 8]);
        bf16x8 pf1 = *reinterpret_cast<bf16x8*>(&Pl[wave][ln * 72 + 32 + quad * 8]);
        for (int dt = 0; dt < 4; dt++) {
            bf16x8 bk0 = *reinterpret_cast<bf16x8*>(&KsT[(dt * 16 + ln) * 72 + quad * 8]);
            bf16x8 bk1 = *reinterpret_cast<bf16x8*>(&KsT[(dt * 16 + ln) * 72 + 32 + quad * 8]);
            o[dt] = MFMA(pf0, bk0, o[dt]);
            o[dt] = MFMA(pf1, bk1, o[dt]);
        }
    }

    for (int r = 0; r < 4; r++)
        for (int off = 1; off < 16; off <<= 1) lst[r] += __shfl_xor(lst[r], off, 64);

    u16* out = CTXH + (size_t)bh * 65536;
    for (int r = 0; r < 4; r++) {
        float inv = 1.0f / lst[r];
        int row = lw + quad * 4 + r;
        for (int dt = 0; dt < 4; dt++)
            out[(size_t)row * 64 + dt * 16 + ln] = f2bf(o[dt][r] * inv);
    }
}

// ---------------- layernorm over 768, one block per row; optional second input ----------------
__global__ __launch_bounds__(256) void layernorm_k(const float* __restrict__ in,
                                                   float* __restrict__ outF,
                                                   u16* __restrict__ outB,
                                                   const float* __restrict__ g,
                                                   const float* __restrict__ be,
                                                   const float* __restrict__ in2) {
    __shared__ float red[8];
    int row = blockIdx.x;
    int t = threadIdx.x;
    const float* p = in + (size_t)row * 768;
    float v0 = p[t], v1 = p[t + 256], v2 = p[t + 512];
    if (in2) {
        const float* p2 = in2 + (size_t)row * 768;
        v0 += p2[t]; v1 += p2[t + 256]; v2 += p2[t + 512];
    }
    float s = v0 + v1 + v2;
    float ss = v0 * v0 + v1 * v1 + v2 * v2;
    for (int off = 32; off >= 1; off >>= 1) {
        s += __shfl_xor(s, off, 64);
        ss += __shfl_xor(ss, off, 64);
    }
    int wave = t >> 6, lane = t & 63;
    if (lane == 0) { red[wave] = s; red[4 + wave] = ss; }
    __syncthreads();
    float S = red[0] + red[1] + red[2] + red[3];
    float SS = red[4] + red[5] + red[6] + red[7];
    float mean = S * (1.0f / 768.0f);
    float var = SS * (1.0f / 768.0f) - mean * mean;
    float rstd = rsqrtf(var + 1e-5f);
    float o0 = (v0 - mean) * rstd * g[t] + be[t];
    float o1 = (v1 - mean) * rstd * g[t + 256] + be[t + 256];
    float o2 = (v2 - mean) * rstd * g[t + 512] + be[t + 512];
    float* q = outF + (size_t)row * 768;
    q[t] = o0; q[t + 256] = o1; q[t + 512] = o2;
    if (outB) {
        u16* qb = outB + (size_t)row * 768;
        qb[t] = f2bf(o0); qb[t + 256] = f2bf(o1); qb[t + 512] = f2bf(o2);
    }
}

extern "C" void kernel_launch(void* const* d_in, const int* in_sizes, int n_in,
                              void* d_out, int out_size, void* d_ws, size_t ws_size,
                              hipStream_t stream) {
    const float* x   = (const float*)d_in[0];
    const float* Wq  = (const float*)d_in[1];
    const float* Wk  = (const float*)d_in[2];
    // d_in[3] = Wv — dead code in the reference, skipped.
    const float* Wo  = (const float*)d_in[4];
    const float* W1  = (const float*)d_in[5];
    const float* b1  = (const float*)d_in[6];
    const float* W2  = (const float*)d_in[7];
    const float* b2  = (const float*)d_in[8];
    const float* g1  = (const float*)d_in[9];
    const float* be1 = (const float*)d_in[10];
    const float* g2  = (const float*)d_in[11];
    const float* be2 = (const float*)d_in[12];
    float* out = (float*)d_out;

    const int S = 8192, H = 768, MLP4 = 3072, H2 = 1536;

    char* ws = (char*)d_ws;
    u16* XB   = (u16*)ws;  ws += (size_t)S * H * 2;      // reused as CTXH
    u16* WQKT = (u16*)ws;  ws += (size_t)H2 * H * 2;
    u16* WOT  = (u16*)ws;  ws += (size_t)H * H * 2;      // k-permuted
    u16* W1T  = (u16*)ws;  ws += (size_t)H * MLP4 * 2;
    u16* W2T  = (u16*)ws;  ws += (size_t)H * MLP4 * 2;
    u16* QKB  = (u16*)ws;  ws += (size_t)S * H2 * 2;     // Q (log2-prescaled) | K, row-major
    u16* KH   = (u16*)ws;  ws += (size_t)S * H * 2;      // K head-major
    float* Y  = (float*)ws; ws += (size_t)S * H * 4;
    u16* HB   = (u16*)ws;  ws += (size_t)S * MLP4 * 2;

    u16* CTXH = XB;          // after QK gemm, XB is dead
    u16* X1B  = QKB;         // Q half, dead after attention
    u16* KHT  = HB;          // HB dead until W1 gemm; holds K transposed (12.6 MB < 50 MB)

    // 1. fused prep: x cast + all weight transposes
    prep_k<<<4608, 256, 0, stream>>>(x, Wq, Wk, Wo, W1, W2, XB, WQKT, WOT, W1T, W2T);

    // 2. [Q|K] = X [Wq|Wk]  — 512-thread 8-wave variant
    gemm_bt_k<4, 128, false, 0, false, 512><<<12 * 64, 512, 0, stream>>>(XB, WQKT, S, H2, H, 12, nullptr, QKB, nullptr, nullptr);

    // 3. attention (K repacked head-major + transposed; ctx stays head-major in CTXH)
    head_pack_k<<<dim3(64, 8), 256, 0, stream>>>(QKB + H, H2, KH, KHT);
    attention_k<<<dim3(16, 96), 256, 0, stream>>>(QKB, H2, KH, KHT, CTXH);

    // 4. y = x + ctx Wo ; x1 = LN1(y) in-place + bf16 copy
    //    Wo: fat tile TM=128/NT=512/NSO=4 (r19-confirmed mechanism: block-steps/CU 72 -> 36)
    gemm_bt_k<1, 128, true, 4, false, 512><<<6 * 64, 512, 0, stream>>>(CTXH, WOT, S, H, H, 6, Y, nullptr, x, nullptr);
    layernorm_k<<<S, 256, 0, stream>>>(Y, Y, X1B, g1, be1, nullptr);

    // 5. h = gelu(x1 W1 + b1) ; y2 = x1 + h W2 + b2 ; out = LN2(y2)
    //    W1: 512-thread 8-wave. W2: TM=128 fat tile, NSO=4 (r19: confirmed win).
    gemm_bt_k<2, 128, false, 0, false, 512><<<24 * 64, 512, 0, stream>>>(X1B, W1T, S, MLP4, H, 24, nullptr, HB, nullptr, b1);
    gemm_bt_k<3, 128, false, 4, false, 512><<<6 * 64, 512, 0, stream>>>(HB, W2T, S, H, MLP4, 6, Y, nullptr, Y, b2);
    layernorm_k<<<S, 256, 0, stream>>>(Y, out, nullptr, g2, be2, nullptr);
}

// Round 21
// 368.934 us; speedup vs baseline: 1.1358x; 1.0083x over previous
//
#include <hip/hip_runtime.h>
#include <math.h>

typedef unsigned short u16;
typedef unsigned int u32;
typedef short bf16x8 __attribute__((ext_vector_type(8)));
typedef float f32x4 __attribute__((ext_vector_type(4)));

#define MFMA(a, b, c) __builtin_amdgcn_mfma_f32_16x16x32_bf16((a), (b), (c), 0, 0, 0)

// async global->LDS, 16B per lane; LDS dest = wave-uniform base + lane*16
#define GLOAD_LDS16(g, l)                                                              \
    __builtin_amdgcn_global_load_lds((const __attribute__((address_space(1))) void*)(g), \
                                     (__attribute__((address_space(3))) void*)(l), 16, 0, 0)

__device__ __forceinline__ u16 f2bf(float f) {
    u32 u = __float_as_uint(f);
    u32 r = (u + 0x7fffu + ((u >> 16) & 1u)) >> 16;
    return (u16)r;
}

__device__ __forceinline__ u16 f2bf_trunc(float f) {  // truncating bf16 (1 VALU op)
    return (u16)(__float_as_uint(f) >> 16);
}

// tanh-form GELU via native exp/rcp
__device__ __forceinline__ float fast_gelu(float z) {
    float u = fminf(1.5957691216f * z * (1.0f + 0.044715f * z * z), 80.0f);
    float e = __expf(u);
    float r = __builtin_amdgcn_rcpf(e + 1.0f);
    return z * e * r;
}

// ================= fused prep: x cast + all weight transposes, one dispatch =================
__device__ void dev_xcast(const float* __restrict__ in, u16* __restrict__ out, int blk) {
    size_t i = ((size_t)blk * 256 + threadIdx.x) * 8;
    const float4* p = reinterpret_cast<const float4*>(in + i);
    float4 a = p[0], b = p[1];
    union { u16 u[8]; uint4 v; } o;
    o.u[0] = f2bf(a.x); o.u[1] = f2bf(a.y); o.u[2] = f2bf(a.z); o.u[3] = f2bf(a.w);
    o.u[4] = f2bf(b.x); o.u[5] = f2bf(b.y); o.u[6] = f2bf(b.z); o.u[7] = f2bf(b.w);
    *reinterpret_cast<uint4*>(out + i) = o.v;
}

__device__ void dev_transpose(const float* __restrict__ in, u16* __restrict__ out,
                              int K, int N, int bx, int by, float* tile /* [64][65] */) {
    int k0 = by * 64, n0 = bx * 64;
    int t = threadIdx.x;
    for (int p = 0; p < 16; p++) {
        int idx = t + p * 256;
        int r = idx >> 6, c = idx & 63;
        tile[r * 65 + c] = in[(size_t)(k0 + r) * N + n0 + c];
    }
    __syncthreads();
    for (int p = 0; p < 16; p++) {
        int idx = t + p * 256;
        int nr = idx >> 6, nc = idx & 63;
        out[(size_t)(n0 + nr) * K + k0 + nc] = f2bf(tile[nc * 65 + nr]);
    }
}

// Wo transpose with k-permute: out[col][n*64+d] = Wo[d*12+n][col]
__device__ void dev_wo(const float* __restrict__ in, u16* __restrict__ out,
                       int bx, int by, float* tile /* [96][65] */) {
    int k0 = by * 96, n0 = bx * 64;
    int t = threadIdx.x;
    for (int p = 0; p < 24; p++) {
        int idx = t + p * 256;
        int r = idx >> 6, c = idx & 63;
        tile[r * 65 + c] = in[(size_t)(k0 + r) * 768 + n0 + c];
    }
    __syncthreads();
    for (int p = 0; p < 3; p++) {
        int idx = t + p * 256;  // (col c)*12 + n
        int c = idx / 12, n = idx % 12;
        union { u16 u[8]; uint4 v; } o;
        for (int j = 0; j < 8; j++) o.u[j] = f2bf(tile[(j * 12 + n) * 65 + c]);
        *reinterpret_cast<uint4*>(&out[(size_t)(n0 + c) * 768 + n * 64 + by * 8]) = o.v;
    }
}

__global__ __launch_bounds__(256) void prep_k(const float* __restrict__ x,
                                              const float* __restrict__ Wq,
                                              const float* __restrict__ Wk,
                                              const float* __restrict__ Wo,
                                              const float* __restrict__ W1,
                                              const float* __restrict__ W2,
                                              u16* __restrict__ XB,
                                              u16* __restrict__ WQKT,
                                              u16* __restrict__ WOT,
                                              u16* __restrict__ W1T,
                                              u16* __restrict__ W2T) {
    __shared__ float tile[96 * 65];
    int bid = blockIdx.x;
    if (bid < 3072) {
        dev_xcast(x, XB, bid);
    } else if (bid < 3216) {
        int b = bid - 3072; dev_transpose(Wq, WQKT, 768, 768, b % 12, b / 12, tile);
    } else if (bid < 3360) {
        int b = bid - 3216; dev_transpose(Wk, WQKT + (size_t)768 * 768, 768, 768, b % 12, b / 12, tile);
    } else if (bid < 3456) {
        int b = bid - 3360; dev_wo(Wo, WOT, b % 12, b / 12, tile);
    } else if (bid < 4032) {
        int b = bid - 3456; dev_transpose(W1, W1T, 768, 3072, b % 48, b / 48, tile);
    } else {
        int b = bid - 4032; dev_transpose(W2, W2T, 3072, 768, b % 12, b / 12, tile);
    }
}

// ---------------- head pack: in (S x ld, col base pre-offset) -> KH (96 x 1024 x 64) ----------------
// Also emits KHT (96 x 64 x 1024): KHT[head][d][m] = K[b][m][d*12+n].
__global__ __launch_bounds__(256) void head_pack_k(const u16* __restrict__ in, int ld,
                                                   u16* __restrict__ out,
                                                   u16* __restrict__ outT) {
    __shared__ u16 tile[16 * 768];
    int b = blockIdx.y;
    int l0 = blockIdx.x * 16;
    int t = threadIdx.x;
    for (int p = 0; p < 6; p++) {
        int c = t + p * 256;
        int li = c / 96, dc = c % 96;
        *reinterpret_cast<uint4*>(&tile[li * 768 + dc * 8]) =
            *reinterpret_cast<const uint4*>(&in[(size_t)(b * 1024 + l0 + li) * ld + dc * 8]);
    }
    __syncthreads();
    for (int p = 0; p < 6; p++) {
        int c = t + p * 256;
        int n = c >> 7, rem = c & 127, li = rem >> 3, k8 = rem & 7;
        union { u16 u[8]; uint4 v; } o;
        for (int j = 0; j < 8; j++) o.u[j] = tile[li * 768 + (k8 * 8 + j) * 12 + n];
        *reinterpret_cast<uint4*>(&out[(size_t)((b * 12 + n) * 1024 + l0 + li) * 64 + k8 * 8]) = o.v;
    }
    // transposed copy: 6 passes x 256 threads cover 12 heads x 64 d x 2 halves (8 m each)
    for (int p = 0; p < 6; p++) {
        int c = t + p * 256;                 // 0..1535
        int n = c >> 7;                      // head 0..11
        int rem = c & 127;
        int d = rem >> 1;                    // 0..63
        int half = rem & 1;                  // m-offset 0 or 8
        union { u16 u[8]; uint4 v; } o;
        for (int j = 0; j < 8; j++) o.u[j] = tile[(half * 8 + j) * 768 + d * 12 + n];
        *reinterpret_cast<uint4*>(
            &outT[((size_t)(b * 12 + n) * 64 + d) * 1024 + l0 + half * 8]) = o.v;
    }
}

// ---------------- GEMM: C(MxN) = A(MxK bf16) @ BT(NxK bf16)^T ----------------
// TM x 128 tile, NS-stage pipeline, ONE raw s_barrier per K-step, counted per-wave vmcnt.
// NT=256: 4 waves.  NT=512 + TM=128: 8 waves, 64x32 subtiles.
// NT=512 + TM=64 (ATHIN): 8 waves, 32x32 subtiles; A staged by waves 0-3 only.
// W2/Wo use TM=128/NT=512/NSO=4: halves block count — r19/r20 A/B confirmed the
// per-block-step cost is fixed & occupancy-invariant, so fewer step-slots wins.
// AH: A is CTXH [b*12+n][l][64], logical k = n*64+d (works for any TM; BT rows permuted).
// EPI 1: outF = resid + acc;  2: outB = bf16(gelu(acc + bias[col]));
// EPI 3: outF = resid + acc + bias[col];
// EPI 4: outB = bf16(acc * (col<768 ? 0.125*log2e : 1))  [QK proj; Q in log2-domain]
template <int EPI, int TM, bool AH = false, int NSO = 0, bool KSPLIT = false, int NT = 256>
__global__ __launch_bounds__(NT) void gemm_bt_k(const u16* __restrict__ A,
                                                const u16* __restrict__ BT,
                                                int M, int N, int K, int NBX,
                                                float* __restrict__ outF,
                                                u16* __restrict__ outB,
                                                const float* __restrict__ resid,
                                                const float* __restrict__ bias) {
    constexpr int NS = NSO ? NSO : ((TM == 64) ? 4 : 3);
    constexpr int WN = (NT == 512) ? 4 : 2;          // waves along N
    constexpr int MI = (TM / 2) / 16;                // A-frag repeats per wave
    constexpr int NJ = (128 / WN) / 16;              // B-frag repeats per wave
    constexpr bool ATHIN = (TM == 64 && NT == 512);  // A tile smaller than thread count
    constexpr int ALD = (TM == 128 && NT == 256) ? 2 : 1;  // A loads / thread / step
    constexpr int BLD = (NT == 256) ? 2 : 1;               // B loads / thread / step
    constexpr int LPS = ALD + BLD;
    constexpr int VC = LPS * (NS - 2);               // counted vmcnt at the wait point
    __shared__ __align__(16) u16 As[NS][TM * 32];
    __shared__ __align__(16) u16 Bs[NS][128 * 32];

    int L = blockIdx.x;
    int kp = 0;
    if constexpr (KSPLIT) {
        int half = gridDim.x >> 1;
        if (L >= half) { kp = 1; L -= half; }
    }
    int bx = (L >> 3) % NBX;
    int by = (L / (8 * NBX)) * 8 + (L & 7);
    int m0 = by * TM, n0 = bx * 128;

    int t = threadIdx.x;
    int wave = t >> 6, lane = t & 63;
    int wr = (wave / WN) * (TM / 2), wc = (wave % WN) * (128 / WN);
    int ln = lane & 15, quad = lane >> 4;
    int sw = quad ^ ((ln >> 1) & 3);

    int e0 = t, e1 = t + 256;                        // e1 only used when NT==256
    int r0 = e0 >> 2, c0 = (e0 & 3) ^ ((r0 >> 1) & 3);
    int r1 = e1 >> 2, c1 = (e1 & 3) ^ ((r1 >> 1) & 3);
    int kofs = 0;
    if constexpr (KSPLIT) kofs = kp * (K >> 1);
    int ahk = 0;
    if constexpr (KSPLIT && AH) ahk = kp * (K >> 4);
    const u16* A0 = A + (size_t)(m0 + (ATHIN ? (r0 & 63) : r0)) * K + kofs + c0 * 8;
    const u16* A1 = A + (size_t)(m0 + r1) * K + kofs + c1 * 8;  // ALD==2 only
    const u16* B0 = BT + (size_t)(n0 + r0) * K + kofs + c0 * 8;
    const u16* B1 = BT + (size_t)(n0 + r1) * K + kofs + c1 * 8; // BLD==2 only
    const u16* Abase = nullptr;
    if constexpr (AH) {
        int m = m0 + r0;
        Abase = A + ((size_t)(m >> 10) * 12288 + (m & 1023)) * 64;
    }

    int nk = K >> 5;
    if constexpr (KSPLIT) nk >>= 1;

    f32x4 acc[MI][NJ];
    for (int i = 0; i < MI; i++)
        for (int j = 0; j < NJ; j++)
            for (int r = 0; r < 4; r++) acc[i][j][r] = 0.0f;

    for (int s = 0; s < NS - 1; s++) {
        if constexpr (AH) {
            int col8 = ahk + s * 4 + c0;
            GLOAD_LDS16(Abase + (col8 >> 3) * 65536 + (col8 & 7) * 8, &As[s][e0 * 8]);
        } else if constexpr (ATHIN) {
            if (wave < 4) GLOAD_LDS16(A0 + s * 32, &As[s][e0 * 8]);  // wave-uniform guard
        } else {
            GLOAD_LDS16(A0 + s * 32, &As[s][e0 * 8]);
            if constexpr (ALD == 2) GLOAD_LDS16(A1 + s * 32, &As[s][e1 * 8]);
        }
        GLOAD_LDS16(B0 + s * 32, &Bs[s][e0 * 8]);
        if constexpr (BLD == 2) GLOAD_LDS16(B1 + s * 32, &Bs[s][e1 * 8]);
    }

    for (int kb = 0; kb < nk; kb += NS) {
#pragma unroll
        for (int s = 0; s < NS; s++) {
            int k = kb + s;
            if constexpr (ATHIN) {
                // per-wave counted vmcnt: waves 0-3 issue 2 loads/step, waves 4-7 issue 1
                if (wave < 4) asm volatile("s_waitcnt vmcnt(4)" ::: "memory");
                else          asm volatile("s_waitcnt vmcnt(2)" ::: "memory");
            }
            else if constexpr (VC == 6) asm volatile("s_waitcnt vmcnt(6)" ::: "memory");
            else if constexpr (VC == 4) asm volatile("s_waitcnt vmcnt(4)" ::: "memory");
            else if constexpr (VC == 3) asm volatile("s_waitcnt vmcnt(3)" ::: "memory");
            else if constexpr (VC == 2) asm volatile("s_waitcnt vmcnt(2)" ::: "memory");
            else                        asm volatile("s_waitcnt vmcnt(0)" ::: "memory");
            asm volatile("s_barrier" ::: "memory");
            {
                int ks = k + NS - 1 < nk ? k + NS - 1 : nk - 1;  // clamped: uniform in-flight count
                int stage = (s + NS - 1) % NS;  // s constant under unroll -> folds
                if constexpr (AH) {
                    int col8 = ahk + ks * 4 + c0;
                    GLOAD_LDS16(Abase + (col8 >> 3) * 65536 + (col8 & 7) * 8, &As[stage][e0 * 8]);
                } else if constexpr (ATHIN) {
                    if (wave < 4) GLOAD_LDS16(A0 + ks * 32, &As[stage][e0 * 8]);
                } else {
                    GLOAD_LDS16(A0 + ks * 32, &As[stage][e0 * 8]);
                    if constexpr (ALD == 2) GLOAD_LDS16(A1 + ks * 32, &As[stage][e1 * 8]);
                }
                GLOAD_LDS16(B0 + ks * 32, &Bs[stage][e0 * 8]);
                if constexpr (BLD == 2) GLOAD_LDS16(B1 + ks * 32, &Bs[stage][e1 * 8]);
            }
            const u16* as = As[s];
            const u16* bs = Bs[s];
            bf16x8 afr[MI], bfr[NJ];
            for (int i = 0; i < MI; i++)
                afr[i] = *reinterpret_cast<const bf16x8*>(&as[(wr + i * 16 + ln) * 32 + sw * 8]);
            for (int j = 0; j < NJ; j++)
                bfr[j] = *reinterpret_cast<const bf16x8*>(&bs[(wc + j * 16 + ln) * 32 + sw * 8]);
            for (int i = 0; i < MI; i++)
                for (int j = 0; j < NJ; j++)
                    acc[i][j] = MFMA(afr[i], bfr[j], acc[i][j]);
        }
    }

    for (int i = 0; i < MI; i++) {
        for (int j = 0; j < NJ; j++) {
            int col = n0 + wc + j * 16 + ln;
            for (int r = 0; r < 4; r++) {
                int row = m0 + wr + i * 16 + quad * 4 + r;
                size_t idx = (size_t)row * N + col;
                float v = acc[i][j][r];
                if constexpr (EPI == 1) {
                    if constexpr (KSPLIT) {
                        if (kp == 0) outF[idx] = resid[idx] + v;
                        else reinterpret_cast<float*>(outB)[idx] = v;
                    } else {
                        outF[idx] = resid[idx] + v;
                    }
                } else if constexpr (EPI == 2) {
                    outB[idx] = f2bf(fast_gelu(v + bias[col]));
                } else if constexpr (EPI == 3) {
                    if constexpr (KSPLIT) {
                        if (kp == 0) outF[idx] = resid[idx] + v + bias[col];
                        else reinterpret_cast<float*>(outB)[idx] = v;
                    } else {
                        outF[idx] = resid[idx] + v + bias[col];
                    }
                } else {
                    // 0.125 * log2(e): Q scores land in log2 domain for exp2 softmax
                    outB[idx] = f2bf(col < 768 ? v * 0.18033688011112042f : v);
                }
            }
        }
    }
}

// ---------------- flash-style attention (ctx = softmax @ K), Q prescaled to log2 domain ----------------
// 512 threads / 8 waves, 128 q-rows per block (r20: K-tile staged once serves 8 waves;
// halves K re-reads AND per-block fixed costs vs the 64-row version).
// Each wave owns 16 rows; per-wave compute identical to the verified 256-thread version.
__global__ __launch_bounds__(512) void attention_k(const u16* __restrict__ QB, int ldq,
                                                   const u16* __restrict__ KH,
                                                   const u16* __restrict__ KHT,
                                                   u16* __restrict__ CTXH) {
    __shared__ __align__(16) u16 Ks[64 * 72];   // [m'][d]
    __shared__ __align__(16) u16 KsT[64 * 72];  // [d][m']
    __shared__ __align__(16) u16 Pl[8][16 * 72];
    int bh = blockIdx.y;
    int b = bh / 12, n = bh % 12;
    int l0 = blockIdx.x * 128;
    int t = threadIdx.x, wave = t >> 6, lane = t & 63;
    int ln = lane & 15, quad = lane >> 4;
    int lw = l0 + wave * 16;

    // Q A-fragments (strided gather, once per block); Q already scaled by 0.125*log2e
    bf16x8 a0, a1;
    {
        union { u16 u[8]; bf16x8 v; } q0, q1;
        const u16* qrow = QB + (size_t)(b * 1024 + lw + ln) * ldq + n;
        for (int j = 0; j < 8; j++) {
            q0.u[j] = qrow[(quad * 8 + j) * 12];
            q1.u[j] = qrow[(32 + quad * 8 + j) * 12];
        }
        a0 = q0.v; a1 = q1.v;
    }

    f32x4 o[4];
    for (int dt = 0; dt < 4; dt++)
        for (int r = 0; r < 4; r++) o[dt][r] = 0.0f;
    float lst[4];
    for (int r = 0; r < 4; r++) lst[r] = 0.0f;

    const u16* Kbase  = KH  + (size_t)bh * 65536;
    const u16* KTbase = KHT + (size_t)bh * 65536;  // [d][m], 64 rows x 1024
    int mi = t & 63, dsg = (t >> 6) * 8;           // 512 threads: 64 rows x 8 col-groups

    uint4 kv = *reinterpret_cast<const uint4*>(&Kbase[(size_t)mi * 64 + dsg]);
    uint4 kt = *reinterpret_cast<const uint4*>(&KTbase[(size_t)mi * 1024 + dsg]);

    for (int mb = 0; mb < 16; mb++) {
        __syncthreads();
        *reinterpret_cast<uint4*>(&Ks[mi * 72 + dsg]) = kv;
        *reinterpret_cast<uint4*>(&KsT[mi * 72 + dsg]) = kt;
        __syncthreads();

        {
            int mnext = (mb + 1 < 16 ? mb + 1 : 15) * 64;
            kv = *reinterpret_cast<const uint4*>(&Kbase[(size_t)(mnext + mi) * 64 + dsg]);
            kt = *reinterpret_cast<const uint4*>(&KTbase[(size_t)mi * 1024 + mnext + dsg]);
        }

        f32x4 st[4];
        for (int nt = 0; nt < 4; nt++) {
            bf16x8 bk0 = *reinterpret_cast<bf16x8*>(&Ks[(nt * 16 + ln) * 72 + quad * 8]);
            bf16x8 bk1 = *reinterpret_cast<bf16x8*>(&Ks[(nt * 16 + ln) * 72 + 32 + quad * 8]);
            f32x4 z;
            for (int r = 0; r < 4; r++) z[r] = 0.0f;
            z = MFMA(a0, bk0, z);
            st[nt] = MFMA(a1, bk1, z);
        }

        // softmax numerator: p = exp2(st) (st already includes 1/8 * log2e); no max, no clamp
        for (int r = 0; r < 4; r++) {
            int row = quad * 4 + r;
            float psum = 0.0f;
            for (int nt = 0; nt < 4; nt++) {
                float p = exp2f(st[nt][r]);
                psum += p;
                Pl[wave][row * 72 + nt * 16 + ln] = f2bf_trunc(p);
            }
            lst[r] += psum;
        }

        // PV: O += P(16x64) @ K(64x64)   (Pl wave-private: no barrier)
        bf16x8 pf0 = *reinterpret_cast<bf16x8*>(&Pl[wave][ln * 72 + quad * 8]);
        bf16x8 pf1 = *reinterpret_cast<bf16x8*>(&Pl[wave][ln * 72 + 32 + quad * 8]);
        for (int dt = 0; dt < 4; dt++) {
            bf16x8 bk0 = *reinterpret_cast<bf16x8*>(&KsT[(dt * 16 + ln) * 72 + quad * 8]);
            bf16x8 bk1 = *reinterpret_cast<bf16x8*>(&KsT[(dt * 16 + ln) * 72 + 32 + quad * 8]);
            o[dt] = MFMA(pf0, bk0, o[dt]);
            o[dt] = MFMA(pf1, bk1, o[dt]);
        }
    }

    for (int r = 0; r < 4; r++)
        for (int off = 1; off < 16; off <<= 1) lst[r] += __shfl_xor(lst[r], off, 64);

    u16* out = CTXH + (size_t)bh * 65536;
    for (int r = 0; r < 4; r++) {
        float inv = 1.0f / lst[r];
        int row = lw + quad * 4 + r;
        for (int dt = 0; dt < 4; dt++)
            out[(size_t)row * 64 + dt * 16 + ln] = f2bf(o[dt][r] * inv);
    }
}

// ---------------- layernorm over 768, one block per row; optional second input ----------------
__global__ __launch_bounds__(256) void layernorm_k(const float* __restrict__ in,
                                                   float* __restrict__ outF,
                                                   u16* __restrict__ outB,
                                                   const float* __restrict__ g,
                                                   const float* __restrict__ be,
                                                   const float* __restrict__ in2) {
    __shared__ float red[8];
    int row = blockIdx.x;
    int t = threadIdx.x;
    const float* p = in + (size_t)row * 768;
    float v0 = p[t], v1 = p[t + 256], v2 = p[t + 512];
    if (in2) {
        const float* p2 = in2 + (size_t)row * 768;
        v0 += p2[t]; v1 += p2[t + 256]; v2 += p2[t + 512];
    }
    float s = v0 + v1 + v2;
    float ss = v0 * v0 + v1 * v1 + v2 * v2;
    for (int off = 32; off >= 1; off >>= 1) {
        s += __shfl_xor(s, off, 64);
        ss += __shfl_xor(ss, off, 64);
    }
    int wave = t >> 6, lane = t & 63;
    if (lane == 0) { red[wave] = s; red[4 + wave] = ss; }
    __syncthreads();
    float S = red[0] + red[1] + red[2] + red[3];
    float SS = red[4] + red[5] + red[6] + red[7];
    float mean = S * (1.0f / 768.0f);
    float var = SS * (1.0f / 768.0f) - mean * mean;
    float rstd = rsqrtf(var + 1e-5f);
    float o0 = (v0 - mean) * rstd * g[t] + be[t];
    float o1 = (v1 - mean) * rstd * g[t + 256] + be[t + 256];
    float o2 = (v2 - mean) * rstd * g[t + 512] + be[t + 512];
    float* q = outF + (size_t)row * 768;
    q[t] = o0; q[t + 256] = o1; q[t + 512] = o2;
    if (outB) {
        u16* qb = outB + (size_t)row * 768;
        qb[t] = f2bf(o0); qb[t + 256] = f2bf(o1); qb[t + 512] = f2bf(o2);
    }
}

extern "C" void kernel_launch(void* const* d_in, const int* in_sizes, int n_in,
                              void* d_out, int out_size, void* d_ws, size_t ws_size,
                              hipStream_t stream) {
    const float* x   = (const float*)d_in[0];
    const float* Wq  = (const float*)d_in[1];
    const float* Wk  = (const float*)d_in[2];
    // d_in[3] = Wv — dead code in the reference, skipped.
    const float* Wo  = (const float*)d_in[4];
    const float* W1  = (const float*)d_in[5];
    const float* b1  = (const float*)d_in[6];
    const float* W2  = (const float*)d_in[7];
    const float* b2  = (const float*)d_in[8];
    const float* g1  = (const float*)d_in[9];
    const float* be1 = (const float*)d_in[10];
    const float* g2  = (const float*)d_in[11];
    const float* be2 = (const float*)d_in[12];
    float* out = (float*)d_out;

    const int S = 8192, H = 768, MLP4 = 3072, H2 = 1536;

    char* ws = (char*)d_ws;
    u16* XB   = (u16*)ws;  ws += (size_t)S * H * 2;      // reused as CTXH
    u16* WQKT = (u16*)ws;  ws += (size_t)H2 * H * 2;
    u16* WOT  = (u16*)ws;  ws += (size_t)H * H * 2;      // k-permuted
    u16* W1T  = (u16*)ws;  ws += (size_t)H * MLP4 * 2;
    u16* W2T  = (u16*)ws;  ws += (size_t)H * MLP4 * 2;
    u16* QKB  = (u16*)ws;  ws += (size_t)S * H2 * 2;     // Q (log2-prescaled) | K, row-major
    u16* KH   = (u16*)ws;  ws += (size_t)S * H * 2;      // K head-major
    float* Y  = (float*)ws; ws += (size_t)S * H * 4;
    u16* HB   = (u16*)ws;  ws += (size_t)S * MLP4 * 2;

    u16* CTXH = XB;          // after QK gemm, XB is dead
    u16* X1B  = QKB;         // Q half, dead after attention
    u16* KHT  = HB;          // HB dead until W1 gemm; holds K transposed (12.6 MB < 50 MB)

    // 1. fused prep: x cast + all weight transposes
    prep_k<<<4608, 256, 0, stream>>>(x, Wq, Wk, Wo, W1, W2, XB, WQKT, WOT, W1T, W2T);

    // 2. [Q|K] = X [Wq|Wk]  — 512-thread 8-wave variant
    gemm_bt_k<4, 128, false, 0, false, 512><<<12 * 64, 512, 0, stream>>>(XB, WQKT, S, H2, H, 12, nullptr, QKB, nullptr, nullptr);

    // 3. attention (K repacked head-major + transposed; ctx stays head-major in CTXH)
    //    128 q-rows per block, 8 waves (r20 coarsening: halves K staging + re-fetch)
    head_pack_k<<<dim3(64, 8), 256, 0, stream>>>(QKB + H, H2, KH, KHT);
    attention_k<<<dim3(8, 96), 512, 0, stream>>>(QKB, H2, KH, KHT, CTXH);

    // 4. y = x + ctx Wo ; x1 = LN1(y) in-place + bf16 copy
    //    Wo: fat tile TM=128/NT=512/NSO=4 (r20-confirmed)
    gemm_bt_k<1, 128, true, 4, false, 512><<<6 * 64, 512, 0, stream>>>(CTXH, WOT, S, H, H, 6, Y, nullptr, x, nullptr);
    layernorm_k<<<S, 256, 0, stream>>>(Y, Y, X1B, g1, be1, nullptr);

    // 5. h = gelu(x1 W1 + b1) ; y2 = x1 + h W2 + b2 ; out = LN2(y2)
    //    W1: 512-thread 8-wave. W2: TM=128 fat tile, NSO=4 (r19: confirmed win).
    gemm_bt_k<2, 128, false, 0, false, 512><<<24 * 64, 512, 0, stream>>>(X1B, W1T, S, MLP4, H, 24, nullptr, HB, nullptr, b1);
    gemm_bt_k<3, 128, false, 4, false, 512><<<6 * 64, 512, 0, stream>>>(HB, W2T, S, H, MLP4, 6, Y, nullptr, Y, b2);
    layernorm_k<<<S, 256, 0, stream>>>(Y, out, nullptr, g2, be2, nullptr);
}